// Round 1
// baseline (4464.922 us; speedup 1.0000x reference)
//
#include <hip/hip_runtime.h>
#include <cstddef>

#define BSZ   8192
#define DIM   1024
#define NCON  64
#define NBANK 100000
#define NCLS  1000
#define TOPK  50

#define Y_OFF 8192000
#define S_OFF 16384000

// ---------------- K1: G = C^T C  (G[i][j] = sum_d c[d][i]*c[d][j]) ----------------
__global__ void __launch_bounds__(256) g_kernel(const float* __restrict__ cpt,
                                                float* __restrict__ G) {
    int i = blockIdx.x >> 6, j = blockIdx.x & 63;
    int t = threadIdx.x;
    float s = 0.f;
    for (int d = t; d < DIM; d += 256)
        s += cpt[d * NCON + i] * cpt[d * NCON + j];
    #pragma unroll
    for (int o = 32; o > 0; o >>= 1) s += __shfl_down(s, o);
    __shared__ float ws[4];
    if ((t & 63) == 0) ws[t >> 6] = s;
    __syncthreads();
    if (t == 0) G[blockIdx.x] = ws[0] + ws[1] + ws[2] + ws[3];
}

// ---------------- K2: invG via Gauss-Jordan (G is SPD, well-conditioned) ----------------
__global__ void __launch_bounds__(256) invert_kernel(const float* __restrict__ G,
                                                     float* __restrict__ invG) {
    __shared__ float Ag[64][129];
    __shared__ float fac[64];
    int t = threadIdx.x;
    for (int u = t; u < 64 * 64; u += 256) {
        int i = u >> 6, j = u & 63;
        Ag[i][j] = G[u];
        Ag[i][64 + j] = (i == j) ? 1.f : 0.f;
    }
    __syncthreads();
    for (int k = 0; k < 64; ++k) {
        float piv = Ag[k][k];
        __syncthreads();
        float rp = 1.f / piv;
        if (t < 128) Ag[k][t] *= rp;
        if (t < 64) fac[t] = (t == k) ? 0.f : Ag[t][k];
        __syncthreads();
        for (int u = t; u < 64 * 128; u += 256) {
            int i = u >> 7, j = u & 127;
            if (i != k) Ag[i][j] -= fac[i] * Ag[k][j];
        }
        __syncthreads();
    }
    for (int u = t; u < 64 * 64; u += 256)
        invG[u] = Ag[u >> 6][64 + (u & 63)];
}

// ---------------- K3: B = (X @ C) @ invG   [8192 x 64] ----------------
__global__ void __launch_bounds__(256) projB_kernel(const float* __restrict__ X,
                                                    const float* __restrict__ cpt,
                                                    const float* __restrict__ invG,
                                                    float* __restrict__ B) {
    __shared__ float Cs[64][64];
    __shared__ float Xs[4][64];
    __shared__ float iGs[64][64];
    __shared__ float Asm[4][65];
    int t = threadIdx.x;
    int r = t >> 6, n = t & 63;
    int row0 = blockIdx.x * 4;
    for (int u = t; u < 4096; u += 256) iGs[u >> 6][u & 63] = invG[u];
    float acc = 0.f;
    for (int kk = 0; kk < DIM; kk += 64) {
        Xs[r][n] = X[(row0 + r) * DIM + kk + n];
        for (int u = t; u < 4096; u += 256)
            Cs[u >> 6][u & 63] = cpt[(kk + (u >> 6)) * NCON + (u & 63)];
        __syncthreads();
        #pragma unroll 16
        for (int d = 0; d < 64; ++d) acc += Xs[r][d] * Cs[d][n];
        __syncthreads();
    }
    Asm[r][n] = acc;
    __syncthreads();
    float b = 0.f;
    #pragma unroll 16
    for (int j = 0; j < 64; ++j) b += Asm[r][j] * iGs[j][n];
    B[(row0 + r) * NCON + n] = b;
}

// ---------------- K4: M = C^T @ W_h   [64 x 1000] ----------------
__global__ void __launch_bounds__(256) m_kernel(const float* __restrict__ cpt,
                                                const float* __restrict__ Wh,
                                                float* __restrict__ M) {
    __shared__ float Cs[64][64];
    __shared__ float Wsm[64][17];
    int t = threadIdx.x;
    int c0 = blockIdx.x * 16;
    int cl = t & 15;
    int n0 = t >> 4;  // n = n0 + 16*i
    float acc[4] = {0.f, 0.f, 0.f, 0.f};
    for (int kk = 0; kk < DIM; kk += 64) {
        for (int u = t; u < 4096; u += 256)
            Cs[u >> 6][u & 63] = cpt[(kk + (u >> 6)) * NCON + (u & 63)];
        for (int u = t; u < 1024; u += 256) {
            int d = u >> 4, c = u & 15;
            int gc = c0 + c;
            Wsm[d][c] = (gc < NCLS) ? Wh[(kk + d) * NCLS + gc] : 0.f;
        }
        __syncthreads();
        #pragma unroll 8
        for (int d = 0; d < 64; ++d) {
            float w = Wsm[d][cl];
            acc[0] += Cs[d][n0] * w;
            acc[1] += Cs[d][n0 + 16] * w;
            acc[2] += Cs[d][n0 + 32] * w;
            acc[3] += Cs[d][n0 + 48] * w;
        }
        __syncthreads();
    }
    int gc = c0 + cl;
    if (gc < NCLS) {
        #pragma unroll
        for (int i = 0; i < 4; ++i) M[(n0 + 16 * i) * NCLS + gc] = acc[i];
    }
}

// ---------------- K5: key[n][j] = bank_sq[j] - 2*(c_n . bank_j), bank_sq ----------------
__global__ void __launch_bounds__(256) dist_kernel(const float* __restrict__ bank,
                                                   const float* __restrict__ cpt,
                                                   float* __restrict__ key,
                                                   float* __restrict__ bank_sq) {
    __shared__ float Bs[64][17];
    __shared__ float Cs[16][64];
    __shared__ float sq4[4][64];
    __shared__ float sqs[64];
    int t = threadIdx.x;
    int j0 = blockIdx.x * 64;
    int jl = t & 15;   // j = jl + 16*jj
    int nq = t >> 4;   // n = nq*4 + nn
    int jrow = t & 63, part = t >> 6;
    float acc[4][4] = {};
    float sqacc = 0.f;
    for (int kk = 0; kk < DIM; kk += 16) {
        for (int u = t; u < 1024; u += 256) {
            int i = u >> 4, j = u & 15;
            int gj = j0 + i;
            Bs[i][j] = (gj < NBANK) ? bank[(size_t)gj * DIM + kk + j] : 0.f;
        }
        for (int u = t; u < 1024; u += 256)
            Cs[u >> 6][u & 63] = cpt[(kk + (u >> 6)) * NCON + (u & 63)];
        __syncthreads();
        #pragma unroll
        for (int q = 0; q < 4; ++q) {
            float v = Bs[jrow][part * 4 + q];
            sqacc += v * v;
        }
        #pragma unroll
        for (int kd = 0; kd < 16; ++kd) {
            float a[4], c[4];
            #pragma unroll
            for (int jj = 0; jj < 4; ++jj) a[jj] = Bs[jl + 16 * jj][kd];
            #pragma unroll
            for (int nn = 0; nn < 4; ++nn) c[nn] = Cs[kd][nq * 4 + nn];
            #pragma unroll
            for (int nn = 0; nn < 4; ++nn)
                #pragma unroll
                for (int jj = 0; jj < 4; ++jj) acc[nn][jj] += c[nn] * a[jj];
        }
        __syncthreads();
    }
    sq4[part][jrow] = sqacc;
    __syncthreads();
    if (t < 64) {
        float s = sq4[0][t] + sq4[1][t] + sq4[2][t] + sq4[3][t];
        sqs[t] = s;
        if (j0 + t < NBANK) bank_sq[j0 + t] = s;
    }
    __syncthreads();
    #pragma unroll
    for (int nn = 0; nn < 4; ++nn)
        #pragma unroll
        for (int jj = 0; jj < 4; ++jj) {
            int gj = j0 + jl + 16 * jj;
            if (gj < NBANK)
                key[(size_t)(nq * 4 + nn) * NBANK + gj] = sqs[jl + 16 * jj] - 2.f * acc[nn][jj];
        }
}

// ---------------- K6: top-50 smallest key per concept, sum recovered dots ----------------
// 50 passes of "lexicographic argmin strictly greater than previous (v,j)" — no mutation.
__global__ void __launch_bounds__(256) topk_kernel(const float* __restrict__ key,
                                                   const float* __restrict__ bank_sq,
                                                   float* __restrict__ dots) {
    int n = blockIdx.x;
    const float* row = key + (size_t)n * NBANK;
    int t = threadIdx.x;
    __shared__ float s_pv;
    __shared__ int s_pj;
    __shared__ float wv[4];
    __shared__ int wj[4];
    float pv = -__builtin_inff();
    int pj = -1;
    float sum = 0.f;
    for (int it = 0; it < TOPK; ++it) {
        float bv = __builtin_inff();
        int bj = 0x7fffffff;
        #pragma unroll 4
        for (int j = t; j < NBANK; j += 256) {
            float v = row[j];
            bool gt_prev = (v > pv) || (v == pv && j > pj);
            bool lt_best = (v < bv) || (v == bv && j < bj);
            if (gt_prev && lt_best) { bv = v; bj = j; }
        }
        #pragma unroll
        for (int o = 32; o > 0; o >>= 1) {
            float ov = __shfl_down(bv, o);
            int oj = __shfl_down(bj, o);
            if (ov < bv || (ov == bv && oj < bj)) { bv = ov; bj = oj; }
        }
        int wid = t >> 6;
        if ((t & 63) == 0) { wv[wid] = bv; wj[wid] = bj; }
        __syncthreads();
        if (t == 0) {
            #pragma unroll
            for (int w = 1; w < 4; ++w)
                if (wv[w] < bv || (wv[w] == bv && wj[w] < bj)) { bv = wv[w]; bj = wj[w]; }
            s_pv = bv; s_pj = bj;
            sum += 0.5f * (bank_sq[bj] - bv);  // cb = (bank_sq - key)/2
        }
        __syncthreads();
        pv = s_pv; pj = s_pj;
    }
    if (t == 0) dots[n] = sum / (float)TOPK;
}

// ---------------- K7: the three scalars ----------------
__global__ void __launch_bounds__(256) finalize_kernel(const float* __restrict__ G,
                                                       const float* __restrict__ dots,
                                                       float* __restrict__ out3) {
    __shared__ float r1[256], r2[256], r3[256];
    int t = threadIdx.x;
    float sd = 0.f, so = 0.f;
    for (int u = t; u < 4096; u += 256) {
        float g = G[u];
        if ((u >> 6) == (u & 63)) sd += g; else so += g;
    }
    float s1 = (t < NCON) ? dots[t] : 0.f;
    r1[t] = sd; r2[t] = so; r3[t] = s1;
    __syncthreads();
    for (int o = 128; o > 0; o >>= 1) {
        if (t < o) { r1[t] += r1[t + o]; r2[t] += r2[t + o]; r3[t] += r3[t + o]; }
        __syncthreads();
    }
    if (t == 0) {
        out3[0] = r3[0] / 64.f;    // L_sparse_1
        out3[1] = r2[0] / 4096.f;  // L_sparse_2 (off-diag mean incl. zeros)
        out3[2] = r1[0] / 4096.f;  // norm_metrics (diag mean)
    }
}

// ---------------- K8: y_pred = B @ M + b_h   [8192 x 1000], K = 64 ----------------
__global__ void __launch_bounds__(256) ypred_kernel(const float* __restrict__ B,
                                                    const float* __restrict__ M,
                                                    const float* __restrict__ bh,
                                                    float* __restrict__ out) {
    __shared__ float Bsm[64][65];
    __shared__ float Ms[64][64];
    int t = threadIdx.x;
    int c0 = blockIdx.x * 64;
    int r0 = blockIdx.y * 64;
    int cl = t & 15, rq = t >> 4;
    for (int u = t; u < 4096; u += 256)
        Bsm[u >> 6][u & 63] = B[(r0 + (u >> 6)) * NCON + (u & 63)];
    for (int u = t; u < 4096; u += 256) {
        int k = u >> 6, c = u & 63;
        int gc = c0 + c;
        Ms[k][c] = (gc < NCLS) ? M[k * NCLS + gc] : 0.f;
    }
    __syncthreads();
    float acc[4][4] = {};
    #pragma unroll 8
    for (int k = 0; k < 64; ++k) {
        float a[4], w[4];
        #pragma unroll
        for (int ii = 0; ii < 4; ++ii) a[ii] = Bsm[rq * 4 + ii][k];
        #pragma unroll
        for (int jj = 0; jj < 4; ++jj) w[jj] = Ms[k][cl + 16 * jj];
        #pragma unroll
        for (int ii = 0; ii < 4; ++ii)
            #pragma unroll
            for (int jj = 0; jj < 4; ++jj) acc[ii][jj] += a[ii] * w[jj];
    }
    #pragma unroll
    for (int ii = 0; ii < 4; ++ii)
        #pragma unroll
        for (int jj = 0; jj < 4; ++jj) {
            int row = r0 + rq * 4 + ii;
            int col = c0 + cl + 16 * jj;
            if (col < NCLS) out[row * NCLS + col] = acc[ii][jj] + bh[col];
        }
}

// ---------------- K9: orig_pred = X @ W_h + b_h   [8192 x 1000], K = 1024 ----------------
// Runs LAST: overwrites the scratch that lives in the orig_pred region.
__global__ void __launch_bounds__(256) orig_kernel(const float* __restrict__ X,
                                                   const float* __restrict__ Wh,
                                                   const float* __restrict__ bh,
                                                   float* __restrict__ out) {
    __shared__ float As[64][17];
    __shared__ float Wsm[16][64];
    int t = threadIdx.x;
    int c0 = blockIdx.x * 64;
    int r0 = blockIdx.y * 64;
    int cl = t & 15, rq = t >> 4;
    float acc[4][4] = {};
    for (int kk = 0; kk < DIM; kk += 16) {
        for (int u = t; u < 1024; u += 256) {
            int i = u >> 4, j = u & 15;
            As[i][j] = X[(r0 + i) * DIM + kk + j];
        }
        for (int u = t; u < 1024; u += 256) {
            int k = u >> 6, c = u & 63;
            int gc = c0 + c;
            Wsm[k][c] = (gc < NCLS) ? Wh[(kk + k) * NCLS + gc] : 0.f;
        }
        __syncthreads();
        #pragma unroll
        for (int kd = 0; kd < 16; ++kd) {
            float a[4], w[4];
            #pragma unroll
            for (int ii = 0; ii < 4; ++ii) a[ii] = As[rq * 4 + ii][kd];
            #pragma unroll
            for (int jj = 0; jj < 4; ++jj) w[jj] = Wsm[kd][cl + 16 * jj];
            #pragma unroll
            for (int ii = 0; ii < 4; ++ii)
                #pragma unroll
                for (int jj = 0; jj < 4; ++jj) acc[ii][jj] += a[ii] * w[jj];
        }
        __syncthreads();
    }
    #pragma unroll
    for (int ii = 0; ii < 4; ++ii)
        #pragma unroll
        for (int jj = 0; jj < 4; ++jj) {
            int row = r0 + rq * 4 + ii;
            int col = c0 + cl + 16 * jj;
            if (col < NCLS) out[row * NCLS + col] = acc[ii][jj] + bh[col];
        }
}

extern "C" void kernel_launch(void* const* d_in, const int* in_sizes, int n_in,
                              void* d_out, int out_size, void* d_ws, size_t ws_size,
                              hipStream_t stream) {
    const float* X    = (const float*)d_in[0];
    const float* cpt  = (const float*)d_in[1];
    const float* bank = (const float*)d_in[2];
    const float* Wh   = (const float*)d_in[3];
    const float* bh   = (const float*)d_in[4];
    float* out = (float*)d_out;

    float* orig  = out;
    float* ypred = out + Y_OFF;
    float* out3  = out + S_OFF;

    // Scratch lives inside the orig_pred region; orig_kernel (last) overwrites it.
    float* key     = out;             // 6,400,000 floats
    float* bank_sq = out + 6400000;   //   100,000
    float* G       = out + 6500000;   //     4,096
    float* invG    = out + 6504096;   //     4,096
    float* B       = out + 6508192;   //   524,288
    float* M       = out + 7032480;   //    64,000
    float* dots    = out + 7096480;   //        64  (ends 7,096,544 < 8,192,000)

    g_kernel<<<4096, 256, 0, stream>>>(cpt, G);
    invert_kernel<<<1, 256, 0, stream>>>(G, invG);
    projB_kernel<<<BSZ / 4, 256, 0, stream>>>(X, cpt, invG, B);
    m_kernel<<<(NCLS + 15) / 16, 256, 0, stream>>>(cpt, Wh, M);
    dist_kernel<<<(NBANK + 63) / 64, 256, 0, stream>>>(bank, cpt, key, bank_sq);
    topk_kernel<<<NCON, 256, 0, stream>>>(key, bank_sq, dots);
    finalize_kernel<<<1, 256, 0, stream>>>(G, dots, out3);
    ypred_kernel<<<dim3(16, 128), 256, 0, stream>>>(B, M, bh, ypred);
    orig_kernel<<<dim3(16, 128), 256, 0, stream>>>(X, Wh, bh, orig);
}

// Round 2
// 1508.895 us; speedup vs baseline: 2.9591x; 2.9591x over previous
//
#include <hip/hip_runtime.h>
#include <cstddef>

#define BSZ   8192
#define DIM   1024
#define NCON  64
#define NBANK 100000
#define NCLS  1000
#define TOPK  50
#define NCHUNK 32
#define CHUNK  3125   // 32 * 3125 = 100000

#define Y_OFF 8192000
#define S_OFF 16384000

// ---------------- K1: G = C^T C  (G[i][j] = sum_d c[d][i]*c[d][j]) ----------------
__global__ void __launch_bounds__(256) g_kernel(const float* __restrict__ cpt,
                                                float* __restrict__ G) {
    int i = blockIdx.x >> 6, j = blockIdx.x & 63;
    int t = threadIdx.x;
    float s = 0.f;
    for (int d = t; d < DIM; d += 256)
        s += cpt[d * NCON + i] * cpt[d * NCON + j];
    #pragma unroll
    for (int o = 32; o > 0; o >>= 1) s += __shfl_down(s, o);
    __shared__ float ws[4];
    if ((t & 63) == 0) ws[t >> 6] = s;
    __syncthreads();
    if (t == 0) G[blockIdx.x] = ws[0] + ws[1] + ws[2] + ws[3];
}

// ---------------- K2: invG via Gauss-Jordan (G is SPD, well-conditioned) ----------------
__global__ void __launch_bounds__(256) invert_kernel(const float* __restrict__ G,
                                                     float* __restrict__ invG) {
    __shared__ float Ag[64][129];
    __shared__ float fac[64];
    int t = threadIdx.x;
    for (int u = t; u < 64 * 64; u += 256) {
        int i = u >> 6, j = u & 63;
        Ag[i][j] = G[u];
        Ag[i][64 + j] = (i == j) ? 1.f : 0.f;
    }
    __syncthreads();
    for (int k = 0; k < 64; ++k) {
        float piv = Ag[k][k];
        __syncthreads();
        float rp = 1.f / piv;
        if (t < 128) Ag[k][t] *= rp;
        if (t < 64) fac[t] = (t == k) ? 0.f : Ag[t][k];
        __syncthreads();
        for (int u = t; u < 64 * 128; u += 256) {
            int i = u >> 7, j = u & 127;
            if (i != k) Ag[i][j] -= fac[i] * Ag[k][j];
        }
        __syncthreads();
    }
    for (int u = t; u < 64 * 64; u += 256)
        invG[u] = Ag[u >> 6][64 + (u & 63)];
}

// ---------------- K3: B = (X @ C) @ invG   [8192 x 64] ----------------
__global__ void __launch_bounds__(256) projB_kernel(const float* __restrict__ X,
                                                    const float* __restrict__ cpt,
                                                    const float* __restrict__ invG,
                                                    float* __restrict__ B) {
    __shared__ float Cs[64][64];
    __shared__ float Xs[4][64];
    __shared__ float iGs[64][64];
    __shared__ float Asm[4][65];
    int t = threadIdx.x;
    int r = t >> 6, n = t & 63;
    int row0 = blockIdx.x * 4;
    for (int u = t; u < 4096; u += 256) iGs[u >> 6][u & 63] = invG[u];
    float acc = 0.f;
    for (int kk = 0; kk < DIM; kk += 64) {
        Xs[r][n] = X[(row0 + r) * DIM + kk + n];
        for (int u = t; u < 4096; u += 256)
            Cs[u >> 6][u & 63] = cpt[(kk + (u >> 6)) * NCON + (u & 63)];
        __syncthreads();
        #pragma unroll 16
        for (int d = 0; d < 64; ++d) acc += Xs[r][d] * Cs[d][n];
        __syncthreads();
    }
    Asm[r][n] = acc;
    __syncthreads();
    float b = 0.f;
    #pragma unroll 16
    for (int j = 0; j < 64; ++j) b += Asm[r][j] * iGs[j][n];
    B[(row0 + r) * NCON + n] = b;
}

// ---------------- K4: M = C^T @ W_h   [64 x 1000] ----------------
__global__ void __launch_bounds__(256) m_kernel(const float* __restrict__ cpt,
                                                const float* __restrict__ Wh,
                                                float* __restrict__ M) {
    __shared__ float Cs[64][64];
    __shared__ float Wsm[64][17];
    int t = threadIdx.x;
    int c0 = blockIdx.x * 16;
    int cl = t & 15;
    int n0 = t >> 4;  // n = n0 + 16*i
    float acc[4] = {0.f, 0.f, 0.f, 0.f};
    for (int kk = 0; kk < DIM; kk += 64) {
        for (int u = t; u < 4096; u += 256)
            Cs[u >> 6][u & 63] = cpt[(kk + (u >> 6)) * NCON + (u & 63)];
        for (int u = t; u < 1024; u += 256) {
            int d = u >> 4, c = u & 15;
            int gc = c0 + c;
            Wsm[d][c] = (gc < NCLS) ? Wh[(kk + d) * NCLS + gc] : 0.f;
        }
        __syncthreads();
        #pragma unroll 8
        for (int d = 0; d < 64; ++d) {
            float w = Wsm[d][cl];
            acc[0] += Cs[d][n0] * w;
            acc[1] += Cs[d][n0 + 16] * w;
            acc[2] += Cs[d][n0 + 32] * w;
            acc[3] += Cs[d][n0 + 48] * w;
        }
        __syncthreads();
    }
    int gc = c0 + cl;
    if (gc < NCLS) {
        #pragma unroll
        for (int i = 0; i < 4; ++i) M[(n0 + 16 * i) * NCLS + gc] = acc[i];
    }
}

// ---------------- K5: key[n][j] = bank_sq[j] - 2*(c_n . bank_j), bank_sq ----------------
__global__ void __launch_bounds__(256) dist_kernel(const float* __restrict__ bank,
                                                   const float* __restrict__ cpt,
                                                   float* __restrict__ key,
                                                   float* __restrict__ bank_sq) {
    __shared__ float Bs[64][17];
    __shared__ float Cs[16][64];
    __shared__ float sq4[4][64];
    __shared__ float sqs[64];
    int t = threadIdx.x;
    int j0 = blockIdx.x * 64;
    int jl = t & 15;   // j = jl + 16*jj
    int nq = t >> 4;   // n = nq*4 + nn
    int jrow = t & 63, part = t >> 6;
    float acc[4][4] = {};
    float sqacc = 0.f;
    for (int kk = 0; kk < DIM; kk += 16) {
        for (int u = t; u < 1024; u += 256) {
            int i = u >> 4, j = u & 15;
            int gj = j0 + i;
            Bs[i][j] = (gj < NBANK) ? bank[(size_t)gj * DIM + kk + j] : 0.f;
        }
        for (int u = t; u < 1024; u += 256)
            Cs[u >> 6][u & 63] = cpt[(kk + (u >> 6)) * NCON + (u & 63)];
        __syncthreads();
        #pragma unroll
        for (int q = 0; q < 4; ++q) {
            float v = Bs[jrow][part * 4 + q];
            sqacc += v * v;
        }
        #pragma unroll
        for (int kd = 0; kd < 16; ++kd) {
            float a[4], c[4];
            #pragma unroll
            for (int jj = 0; jj < 4; ++jj) a[jj] = Bs[jl + 16 * jj][kd];
            #pragma unroll
            for (int nn = 0; nn < 4; ++nn) c[nn] = Cs[kd][nq * 4 + nn];
            #pragma unroll
            for (int nn = 0; nn < 4; ++nn)
                #pragma unroll
                for (int jj = 0; jj < 4; ++jj) acc[nn][jj] += c[nn] * a[jj];
        }
        __syncthreads();
    }
    sq4[part][jrow] = sqacc;
    __syncthreads();
    if (t < 64) {
        float s = sq4[0][t] + sq4[1][t] + sq4[2][t] + sq4[3][t];
        sqs[t] = s;
        if (j0 + t < NBANK) bank_sq[j0 + t] = s;
    }
    __syncthreads();
    #pragma unroll
    for (int nn = 0; nn < 4; ++nn)
        #pragma unroll
        for (int jj = 0; jj < 4; ++jj) {
            int gj = j0 + jl + 16 * jj;
            if (gj < NBANK)
                key[(size_t)(nq * 4 + nn) * NBANK + gj] = sqs[jl + 16 * jj] - 2.f * acc[nn][jj];
        }
}

// ---------------- K6a: per-(concept,chunk) top-50 via LDS iterative argmin ----------------
// Block b = concept*32 + chunk. Stage 3125 keys in LDS once, then 50 argmin passes
// marking selected slots +inf (block-local mutation -> deterministic).
__global__ void __launch_bounds__(256) topA_kernel(const float* __restrict__ key,
                                                   float* __restrict__ cand_v,
                                                   int* __restrict__ cand_j) {
    int n = blockIdx.x >> 5;
    int c = blockIdx.x & 31;
    int base = c * CHUNK;
    const float* row = key + (size_t)n * NBANK + base;
    __shared__ float vals[CHUNK];
    __shared__ float wv[4];
    __shared__ int wj[4];
    int t = threadIdx.x;
    for (int j = t; j < CHUNK; j += 256) vals[j] = row[j];
    __syncthreads();
    float* cv = cand_v + (size_t)blockIdx.x * TOPK;
    int* cj = cand_j + (size_t)blockIdx.x * TOPK;
    for (int it = 0; it < TOPK; ++it) {
        float bv = __builtin_inff();
        int bj = 0x7fffffff;
        #pragma unroll 13
        for (int j = t; j < CHUNK; j += 256) {
            float v = vals[j];
            if (v < bv || (v == bv && j < bj)) { bv = v; bj = j; }
        }
        #pragma unroll
        for (int o = 32; o > 0; o >>= 1) {
            float ov = __shfl_down(bv, o);
            int oj = __shfl_down(bj, o);
            if (ov < bv || (ov == bv && oj < bj)) { bv = ov; bj = oj; }
        }
        if ((t & 63) == 0) { wv[t >> 6] = bv; wj[t >> 6] = bj; }
        __syncthreads();
        if (t == 0) {
            #pragma unroll
            for (int w = 1; w < 4; ++w)
                if (wv[w] < bv || (wv[w] == bv && wj[w] < bj)) { bv = wv[w]; bj = wj[w]; }
            cv[it] = bv;
            cj[it] = base + bj;
            vals[bj] = __builtin_inff();
        }
        __syncthreads();
    }
}

// ---------------- K6b: merge 32*50 candidates per concept, sum recovered dots ----------------
__global__ void __launch_bounds__(256) topB_kernel(const float* __restrict__ cand_v,
                                                   const int* __restrict__ cand_j,
                                                   const float* __restrict__ bank_sq,
                                                   float* __restrict__ dots) {
    int n = blockIdx.x;
    const int NC2 = NCHUNK * TOPK;  // 1600
    __shared__ float vals[NCHUNK * TOPK];
    __shared__ int gidx[NCHUNK * TOPK];
    __shared__ float wv[4];
    __shared__ int wj[4], wl[4];
    int t = threadIdx.x;
    for (int j = t; j < NC2; j += 256) {
        vals[j] = cand_v[(size_t)n * NC2 + j];
        gidx[j] = cand_j[(size_t)n * NC2 + j];
    }
    __syncthreads();
    float sum = 0.f;
    for (int it = 0; it < TOPK; ++it) {
        float bv = __builtin_inff();
        int bj = 0x7fffffff;
        int bl = -1;
        #pragma unroll 7
        for (int j = t; j < NC2; j += 256) {
            float v = vals[j];
            int gj = gidx[j];
            if (v < bv || (v == bv && gj < bj)) { bv = v; bj = gj; bl = j; }
        }
        #pragma unroll
        for (int o = 32; o > 0; o >>= 1) {
            float ov = __shfl_down(bv, o);
            int oj = __shfl_down(bj, o);
            int ol = __shfl_down(bl, o);
            if (ov < bv || (ov == bv && oj < bj)) { bv = ov; bj = oj; bl = ol; }
        }
        if ((t & 63) == 0) { wv[t >> 6] = bv; wj[t >> 6] = bj; wl[t >> 6] = bl; }
        __syncthreads();
        if (t == 0) {
            #pragma unroll
            for (int w = 1; w < 4; ++w)
                if (wv[w] < bv || (wv[w] == bv && wj[w] < bj)) { bv = wv[w]; bj = wj[w]; bl = wl[w]; }
            sum += 0.5f * (bank_sq[bj] - bv);  // cb = (bank_sq - key)/2
            vals[bl] = __builtin_inff();
        }
        __syncthreads();
    }
    if (t == 0) dots[n] = sum / (float)TOPK;
}

// ---------------- K7: the three scalars ----------------
__global__ void __launch_bounds__(256) finalize_kernel(const float* __restrict__ G,
                                                       const float* __restrict__ dots,
                                                       float* __restrict__ out3) {
    __shared__ float r1[256], r2[256], r3[256];
    int t = threadIdx.x;
    float sd = 0.f, so = 0.f;
    for (int u = t; u < 4096; u += 256) {
        float g = G[u];
        if ((u >> 6) == (u & 63)) sd += g; else so += g;
    }
    float s1 = (t < NCON) ? dots[t] : 0.f;
    r1[t] = sd; r2[t] = so; r3[t] = s1;
    __syncthreads();
    for (int o = 128; o > 0; o >>= 1) {
        if (t < o) { r1[t] += r1[t + o]; r2[t] += r2[t + o]; r3[t] += r3[t + o]; }
        __syncthreads();
    }
    if (t == 0) {
        out3[0] = r3[0] / 64.f;    // L_sparse_1
        out3[1] = r2[0] / 4096.f;  // L_sparse_2 (off-diag mean incl. zeros)
        out3[2] = r1[0] / 4096.f;  // norm_metrics (diag mean)
    }
}

// ---------------- K8: y_pred = B @ M + b_h   [8192 x 1000], K = 64 ----------------
__global__ void __launch_bounds__(256) ypred_kernel(const float* __restrict__ B,
                                                    const float* __restrict__ M,
                                                    const float* __restrict__ bh,
                                                    float* __restrict__ out) {
    __shared__ float Bsm[64][65];
    __shared__ float Ms[64][64];
    int t = threadIdx.x;
    int c0 = blockIdx.x * 64;
    int r0 = blockIdx.y * 64;
    int cl = t & 15, rq = t >> 4;
    for (int u = t; u < 4096; u += 256)
        Bsm[u >> 6][u & 63] = B[(r0 + (u >> 6)) * NCON + (u & 63)];
    for (int u = t; u < 4096; u += 256) {
        int k = u >> 6, c = u & 63;
        int gc = c0 + c;
        Ms[k][c] = (gc < NCLS) ? M[k * NCLS + gc] : 0.f;
    }
    __syncthreads();
    float acc[4][4] = {};
    #pragma unroll 8
    for (int k = 0; k < 64; ++k) {
        float a[4], w[4];
        #pragma unroll
        for (int ii = 0; ii < 4; ++ii) a[ii] = Bsm[rq * 4 + ii][k];
        #pragma unroll
        for (int jj = 0; jj < 4; ++jj) w[jj] = Ms[k][cl + 16 * jj];
        #pragma unroll
        for (int ii = 0; ii < 4; ++ii)
            #pragma unroll
            for (int jj = 0; jj < 4; ++jj) acc[ii][jj] += a[ii] * w[jj];
    }
    #pragma unroll
    for (int ii = 0; ii < 4; ++ii)
        #pragma unroll
        for (int jj = 0; jj < 4; ++jj) {
            int row = r0 + rq * 4 + ii;
            int col = c0 + cl + 16 * jj;
            if (col < NCLS) out[row * NCLS + col] = acc[ii][jj] + bh[col];
        }
}

// ---------------- K9: orig_pred = X @ W_h + b_h   [8192 x 1000], K = 1024 ----------------
// Runs LAST: overwrites the scratch that lives in the orig_pred region.
__global__ void __launch_bounds__(256) orig_kernel(const float* __restrict__ X,
                                                   const float* __restrict__ Wh,
                                                   const float* __restrict__ bh,
                                                   float* __restrict__ out) {
    __shared__ float As[64][17];
    __shared__ float Wsm[16][64];
    int t = threadIdx.x;
    int c0 = blockIdx.x * 64;
    int r0 = blockIdx.y * 64;
    int cl = t & 15, rq = t >> 4;
    float acc[4][4] = {};
    for (int kk = 0; kk < DIM; kk += 16) {
        for (int u = t; u < 1024; u += 256) {
            int i = u >> 4, j = u & 15;
            As[i][j] = X[(r0 + i) * DIM + kk + j];
        }
        for (int u = t; u < 1024; u += 256) {
            int k = u >> 6, c = u & 63;
            int gc = c0 + c;
            Wsm[k][c] = (gc < NCLS) ? Wh[(kk + k) * NCLS + gc] : 0.f;
        }
        __syncthreads();
        #pragma unroll
        for (int kd = 0; kd < 16; ++kd) {
            float a[4], w[4];
            #pragma unroll
            for (int ii = 0; ii < 4; ++ii) a[ii] = As[rq * 4 + ii][kd];
            #pragma unroll
            for (int jj = 0; jj < 4; ++jj) w[jj] = Wsm[kd][cl + 16 * jj];
            #pragma unroll
            for (int ii = 0; ii < 4; ++ii)
                #pragma unroll
                for (int jj = 0; jj < 4; ++jj) acc[ii][jj] += a[ii] * w[jj];
        }
        __syncthreads();
    }
    #pragma unroll
    for (int ii = 0; ii < 4; ++ii)
        #pragma unroll
        for (int jj = 0; jj < 4; ++jj) {
            int row = r0 + rq * 4 + ii;
            int col = c0 + cl + 16 * jj;
            if (col < NCLS) out[row * NCLS + col] = acc[ii][jj] + bh[col];
        }
}

extern "C" void kernel_launch(void* const* d_in, const int* in_sizes, int n_in,
                              void* d_out, int out_size, void* d_ws, size_t ws_size,
                              hipStream_t stream) {
    const float* X    = (const float*)d_in[0];
    const float* cpt  = (const float*)d_in[1];
    const float* bank = (const float*)d_in[2];
    const float* Wh   = (const float*)d_in[3];
    const float* bh   = (const float*)d_in[4];
    float* out = (float*)d_out;

    float* orig  = out;
    float* ypred = out + Y_OFF;
    float* out3  = out + S_OFF;

    // Scratch lives inside the orig_pred region; orig_kernel (last) overwrites it.
    float* key     = out;             // 6,400,000 floats
    float* bank_sq = out + 6400000;   //   100,000
    float* G       = out + 6500000;   //     4,096
    float* invG    = out + 6504096;   //     4,096
    float* B       = out + 6508192;   //   524,288
    float* M       = out + 7032480;   //    64,000
    float* dots    = out + 7096480;   //        64
    float* cand_v  = out + 7100000;   //   102,400 (64*32*50)
    int*   cand_j  = (int*)(out + 7202400); // 102,400 ints (ends 7,304,800 < 8,192,000)

    g_kernel<<<4096, 256, 0, stream>>>(cpt, G);
    invert_kernel<<<1, 256, 0, stream>>>(G, invG);
    projB_kernel<<<BSZ / 4, 256, 0, stream>>>(X, cpt, invG, B);
    m_kernel<<<(NCLS + 15) / 16, 256, 0, stream>>>(cpt, Wh, M);
    dist_kernel<<<(NBANK + 63) / 64, 256, 0, stream>>>(bank, cpt, key, bank_sq);
    topA_kernel<<<NCON * NCHUNK, 256, 0, stream>>>(key, cand_v, cand_j);
    topB_kernel<<<NCON, 256, 0, stream>>>(cand_v, cand_j, bank_sq, dots);
    finalize_kernel<<<1, 256, 0, stream>>>(G, dots, out3);
    ypred_kernel<<<dim3(16, 128), 256, 0, stream>>>(B, M, bh, ypred);
    orig_kernel<<<dim3(16, 128), 256, 0, stream>>>(X, Wh, bh, orig);
}

// Round 3
// 897.470 us; speedup vs baseline: 4.9750x; 1.6813x over previous
//
#include <hip/hip_runtime.h>
#include <cstddef>

#define BSZ   8192
#define DIM   1024
#define NCON  64
#define NBANK 100000
#define NCLS  1000
#define TOPK  50
#define NCHUNK 32
#define CHUNK  3125   // 32 * 3125 = 100000

#define Y_OFF 8192000
#define S_OFF 16384000

typedef __attribute__((ext_vector_type(8))) short bf16x8;
typedef __attribute__((ext_vector_type(4))) float f32x4;

__device__ __forceinline__ short f2bf(float x) {
    unsigned u = __builtin_bit_cast(unsigned, x);
    unsigned r = (u + 0x7fffu + ((u >> 16) & 1u)) >> 16;
    return (short)r;
}

__device__ __forceinline__ bf16x8 pack8(f32x4 a, f32x4 b) {
    bf16x8 p;
    p[0] = f2bf(a[0]); p[1] = f2bf(a[1]); p[2] = f2bf(a[2]); p[3] = f2bf(a[3]);
    p[4] = f2bf(b[0]); p[5] = f2bf(b[1]); p[6] = f2bf(b[2]); p[7] = f2bf(b[3]);
    return p;
}

// ---------------- K1: G = C^T C ----------------
__global__ void __launch_bounds__(256) g_kernel(const float* __restrict__ cpt,
                                                float* __restrict__ G) {
    int i = blockIdx.x >> 6, j = blockIdx.x & 63;
    int t = threadIdx.x;
    float s = 0.f;
    for (int d = t; d < DIM; d += 256)
        s += cpt[d * NCON + i] * cpt[d * NCON + j];
    #pragma unroll
    for (int o = 32; o > 0; o >>= 1) s += __shfl_down(s, o);
    __shared__ float ws[4];
    if ((t & 63) == 0) ws[t >> 6] = s;
    __syncthreads();
    if (t == 0) G[blockIdx.x] = ws[0] + ws[1] + ws[2] + ws[3];
}

// ---------------- K2: invG via Gauss-Jordan ----------------
__global__ void __launch_bounds__(256) invert_kernel(const float* __restrict__ G,
                                                     float* __restrict__ invG) {
    __shared__ float Ag[64][129];
    __shared__ float fac[64];
    int t = threadIdx.x;
    for (int u = t; u < 64 * 64; u += 256) {
        int i = u >> 6, j = u & 63;
        Ag[i][j] = G[u];
        Ag[i][64 + j] = (i == j) ? 1.f : 0.f;
    }
    __syncthreads();
    for (int k = 0; k < 64; ++k) {
        float piv = Ag[k][k];
        __syncthreads();
        float rp = 1.f / piv;
        if (t < 128) Ag[k][t] *= rp;
        if (t < 64) fac[t] = (t == k) ? 0.f : Ag[t][k];
        __syncthreads();
        for (int u = t; u < 64 * 128; u += 256) {
            int i = u >> 7, j = u & 127;
            if (i != k) Ag[i][j] -= fac[i] * Ag[k][j];
        }
        __syncthreads();
    }
    for (int u = t; u < 64 * 64; u += 256)
        invG[u] = Ag[u >> 6][64 + (u & 63)];
}

// ---------------- K3: B = (X @ C) @ invG   [8192 x 64] ----------------
__global__ void __launch_bounds__(256) projB_kernel(const float* __restrict__ X,
                                                    const float* __restrict__ cpt,
                                                    const float* __restrict__ invG,
                                                    float* __restrict__ B) {
    __shared__ float Cs[64][64];
    __shared__ float Xs[4][64];
    __shared__ float iGs[64][64];
    __shared__ float Asm[4][65];
    int t = threadIdx.x;
    int r = t >> 6, n = t & 63;
    int row0 = blockIdx.x * 4;
    for (int u = t; u < 4096; u += 256) iGs[u >> 6][u & 63] = invG[u];
    float acc = 0.f;
    for (int kk = 0; kk < DIM; kk += 64) {
        Xs[r][n] = X[(row0 + r) * DIM + kk + n];
        for (int u = t; u < 4096; u += 256)
            Cs[u >> 6][u & 63] = cpt[(kk + (u >> 6)) * NCON + (u & 63)];
        __syncthreads();
        #pragma unroll 16
        for (int d = 0; d < 64; ++d) acc += Xs[r][d] * Cs[d][n];
        __syncthreads();
    }
    Asm[r][n] = acc;
    __syncthreads();
    float b = 0.f;
    #pragma unroll 16
    for (int j = 0; j < 64; ++j) b += Asm[r][j] * iGs[j][n];
    B[(row0 + r) * NCON + n] = b;
}

// ---------------- K4: M = C^T @ W_h   [64 x 1000] ----------------
__global__ void __launch_bounds__(256) m_kernel(const float* __restrict__ cpt,
                                                const float* __restrict__ Wh,
                                                float* __restrict__ M) {
    __shared__ float Cs[64][64];
    __shared__ float Wsm[64][17];
    int t = threadIdx.x;
    int c0 = blockIdx.x * 16;
    int cl = t & 15;
    int n0 = t >> 4;
    float acc[4] = {0.f, 0.f, 0.f, 0.f};
    for (int kk = 0; kk < DIM; kk += 64) {
        for (int u = t; u < 4096; u += 256)
            Cs[u >> 6][u & 63] = cpt[(kk + (u >> 6)) * NCON + (u & 63)];
        for (int u = t; u < 1024; u += 256) {
            int d = u >> 4, c = u & 15;
            int gc = c0 + c;
            Wsm[d][c] = (gc < NCLS) ? Wh[(kk + d) * NCLS + gc] : 0.f;
        }
        __syncthreads();
        #pragma unroll 8
        for (int d = 0; d < 64; ++d) {
            float w = Wsm[d][cl];
            acc[0] += Cs[d][n0] * w;
            acc[1] += Cs[d][n0 + 16] * w;
            acc[2] += Cs[d][n0 + 32] * w;
            acc[3] += Cs[d][n0 + 48] * w;
        }
        __syncthreads();
    }
    int gc = c0 + cl;
    if (gc < NCLS) {
        #pragma unroll
        for (int i = 0; i < 4; ++i) M[(n0 + 16 * i) * NCLS + gc] = acc[i];
    }
}

// ---------------- K4b: cptT[n][d] = bf16(cpt[d][n]) ----------------
__global__ void __launch_bounds__(256) cvt_cpt_kernel(const float* __restrict__ cpt,
                                                      short* __restrict__ cptT) {
    int u = blockIdx.x * 256 + threadIdx.x;   // 0 .. 65535
    int n = u >> 10, d = u & 1023;
    cptT[u] = f2bf(cpt[d * NCON + n]);
}

// ---------------- K5: dist via bf16 MFMA ----------------
// key[n][j] = bank_sq[j] - 2 * (cptT[n] . bank[j]) ; bank converted f32->bf16 in-reg,
// bank_sq accumulated in f32 from original values (consistent recovery in topB).
__global__ void __launch_bounds__(256) dist_mfma_kernel(const float* __restrict__ bank,
                                                        const short* __restrict__ cptT,
                                                        float* __restrict__ key,
                                                        float* __restrict__ bank_sq) {
    __shared__ short Bt[128 * 64];   // row j: 64 bf16 = 128B = 8 slots, slot XOR (j&7)
    __shared__ float sqpart[256];
    __shared__ float sqs[128];
    int t = threadIdx.x;
    int j0 = blockIdx.x * 128;
    int wid = t >> 6, l = t & 63;
    int lr = l & 15, lg = l >> 4;
    int sj = t >> 1, sh = t & 1;          // staging: row j=sj, k-half(32)=sh
    bool jv = (j0 + sj) < NBANK;
    const float* srow = bank + (size_t)(j0 + sj) * DIM + sh * 32;
    float sqacc = 0.f;
    f32x4 acc[4][2] = {};
    for (int kk = 0; kk < DIM; kk += 64) {
        f32x4 v[8];
        #pragma unroll
        for (int q = 0; q < 8; ++q) {
            if (jv) v[q] = *(const f32x4*)(srow + kk + q * 4);
            else    v[q] = f32x4{0.f, 0.f, 0.f, 0.f};
        }
        #pragma unroll
        for (int q = 0; q < 8; ++q)
            sqacc += v[q][0]*v[q][0] + v[q][1]*v[q][1] + v[q][2]*v[q][2] + v[q][3]*v[q][3];
        __syncthreads();  // prev-iter frag reads done before overwrite
        #pragma unroll
        for (int q2 = 0; q2 < 4; ++q2) {
            bf16x8 pk = pack8(v[2 * q2], v[2 * q2 + 1]);
            int slot = sh * 4 + q2;
            *(bf16x8*)((char*)Bt + sj * 128 + ((slot ^ (sj & 7)) << 4)) = pk;
        }
        __syncthreads();
        #pragma unroll
        for (int ks = 0; ks < 2; ++ks) {
            bf16x8 af[4], bfr[2];
            #pragma unroll
            for (int mi = 0; mi < 4; ++mi)
                af[mi] = *(const bf16x8*)(cptT + (mi * 16 + lr) * DIM + kk + ks * 32 + lg * 8);
            #pragma unroll
            for (int ni = 0; ni < 2; ++ni) {
                int j = wid * 32 + ni * 16 + lr;
                int slot = ks * 4 + lg;
                bfr[ni] = *(const bf16x8*)((char*)Bt + j * 128 + ((slot ^ (j & 7)) << 4));
            }
            #pragma unroll
            for (int mi = 0; mi < 4; ++mi)
                #pragma unroll
                for (int ni = 0; ni < 2; ++ni)
                    acc[mi][ni] = __builtin_amdgcn_mfma_f32_16x16x32_bf16(af[mi], bfr[ni], acc[mi][ni], 0, 0, 0);
        }
    }
    sqpart[t] = sqacc;
    __syncthreads();
    if ((t & 1) == 0) {
        float s = sqpart[t] + sqpart[t + 1];
        sqs[sj] = s;
        if (jv) bank_sq[j0 + sj] = s;
    }
    __syncthreads();
    #pragma unroll
    for (int mi = 0; mi < 4; ++mi)
        #pragma unroll
        for (int ni = 0; ni < 2; ++ni) {
            int jl = wid * 32 + ni * 16 + lr;
            int j = j0 + jl;
            if (j < NBANK) {
                float s = sqs[jl];
                #pragma unroll
                for (int r = 0; r < 4; ++r) {
                    int m = mi * 16 + lg * 4 + r;
                    key[(size_t)m * NBANK + j] = s - 2.f * acc[mi][ni][r];
                }
            }
        }
}

// ---------------- K6a: per-(concept,chunk) top-50 via LDS iterative argmin ----------------
__global__ void __launch_bounds__(256) topA_kernel(const float* __restrict__ key,
                                                   float* __restrict__ cand_v,
                                                   int* __restrict__ cand_j) {
    int n = blockIdx.x >> 5;
    int c = blockIdx.x & 31;
    int base = c * CHUNK;
    const float* row = key + (size_t)n * NBANK + base;
    __shared__ float vals[CHUNK];
    __shared__ float wv[4];
    __shared__ int wj[4];
    int t = threadIdx.x;
    for (int j = t; j < CHUNK; j += 256) vals[j] = row[j];
    __syncthreads();
    float* cv = cand_v + (size_t)blockIdx.x * TOPK;
    int* cj = cand_j + (size_t)blockIdx.x * TOPK;
    for (int it = 0; it < TOPK; ++it) {
        float bv = __builtin_inff();
        int bj = 0x7fffffff;
        #pragma unroll 13
        for (int j = t; j < CHUNK; j += 256) {
            float v = vals[j];
            if (v < bv || (v == bv && j < bj)) { bv = v; bj = j; }
        }
        #pragma unroll
        for (int o = 32; o > 0; o >>= 1) {
            float ov = __shfl_down(bv, o);
            int oj = __shfl_down(bj, o);
            if (ov < bv || (ov == bv && oj < bj)) { bv = ov; bj = oj; }
        }
        if ((t & 63) == 0) { wv[t >> 6] = bv; wj[t >> 6] = bj; }
        __syncthreads();
        if (t == 0) {
            #pragma unroll
            for (int w = 1; w < 4; ++w)
                if (wv[w] < bv || (wv[w] == bv && wj[w] < bj)) { bv = wv[w]; bj = wj[w]; }
            cv[it] = bv;
            cj[it] = base + bj;
            vals[bj] = __builtin_inff();
        }
        __syncthreads();
    }
}

// ---------------- K6b: merge 32*50 candidates per concept ----------------
__global__ void __launch_bounds__(256) topB_kernel(const float* __restrict__ cand_v,
                                                   const int* __restrict__ cand_j,
                                                   const float* __restrict__ bank_sq,
                                                   float* __restrict__ dots) {
    int n = blockIdx.x;
    const int NC2 = NCHUNK * TOPK;  // 1600
    __shared__ float vals[NCHUNK * TOPK];
    __shared__ int gidx[NCHUNK * TOPK];
    __shared__ float wv[4];
    __shared__ int wj[4], wl[4];
    int t = threadIdx.x;
    for (int j = t; j < NC2; j += 256) {
        vals[j] = cand_v[(size_t)n * NC2 + j];
        gidx[j] = cand_j[(size_t)n * NC2 + j];
    }
    __syncthreads();
    float sum = 0.f;
    for (int it = 0; it < TOPK; ++it) {
        float bv = __builtin_inff();
        int bj = 0x7fffffff;
        int bl = -1;
        #pragma unroll 7
        for (int j = t; j < NC2; j += 256) {
            float v = vals[j];
            int gj = gidx[j];
            if (v < bv || (v == bv && gj < bj)) { bv = v; bj = gj; bl = j; }
        }
        #pragma unroll
        for (int o = 32; o > 0; o >>= 1) {
            float ov = __shfl_down(bv, o);
            int oj = __shfl_down(bj, o);
            int ol = __shfl_down(bl, o);
            if (ov < bv || (ov == bv && oj < bj)) { bv = ov; bj = oj; bl = ol; }
        }
        if ((t & 63) == 0) { wv[t >> 6] = bv; wj[t >> 6] = bj; wl[t >> 6] = bl; }
        __syncthreads();
        if (t == 0) {
            #pragma unroll
            for (int w = 1; w < 4; ++w)
                if (wv[w] < bv || (wv[w] == bv && wj[w] < bj)) { bv = wv[w]; bj = wj[w]; bl = wl[w]; }
            sum += 0.5f * (bank_sq[bj] - bv);
            vals[bl] = __builtin_inff();
        }
        __syncthreads();
    }
    if (t == 0) dots[n] = sum / (float)TOPK;
}

// ---------------- K7: the three scalars ----------------
__global__ void __launch_bounds__(256) finalize_kernel(const float* __restrict__ G,
                                                       const float* __restrict__ dots,
                                                       float* __restrict__ out3) {
    __shared__ float r1[256], r2[256], r3[256];
    int t = threadIdx.x;
    float sd = 0.f, so = 0.f;
    for (int u = t; u < 4096; u += 256) {
        float g = G[u];
        if ((u >> 6) == (u & 63)) sd += g; else so += g;
    }
    float s1 = (t < NCON) ? dots[t] : 0.f;
    r1[t] = sd; r2[t] = so; r3[t] = s1;
    __syncthreads();
    for (int o = 128; o > 0; o >>= 1) {
        if (t < o) { r1[t] += r1[t + o]; r2[t] += r2[t + o]; r3[t] += r3[t + o]; }
        __syncthreads();
    }
    if (t == 0) {
        out3[0] = r3[0] / 64.f;
        out3[1] = r2[0] / 4096.f;
        out3[2] = r1[0] / 4096.f;
    }
}

// ---------------- K8: y_pred = B @ M + b_h   [8192 x 1000], K = 64 ----------------
__global__ void __launch_bounds__(256) ypred_kernel(const float* __restrict__ B,
                                                    const float* __restrict__ M,
                                                    const float* __restrict__ bh,
                                                    float* __restrict__ out) {
    __shared__ float Bsm[64][65];
    __shared__ float Ms[64][64];
    int t = threadIdx.x;
    int c0 = blockIdx.x * 64;
    int r0 = blockIdx.y * 64;
    int cl = t & 15, rq = t >> 4;
    for (int u = t; u < 4096; u += 256)
        Bsm[u >> 6][u & 63] = B[(r0 + (u >> 6)) * NCON + (u & 63)];
    for (int u = t; u < 4096; u += 256) {
        int k = u >> 6, c = u & 63;
        int gc = c0 + c;
        Ms[k][c] = (gc < NCLS) ? M[k * NCLS + gc] : 0.f;
    }
    __syncthreads();
    float acc[4][4] = {};
    #pragma unroll 8
    for (int k = 0; k < 64; ++k) {
        float a[4], w[4];
        #pragma unroll
        for (int ii = 0; ii < 4; ++ii) a[ii] = Bsm[rq * 4 + ii][k];
        #pragma unroll
        for (int jj = 0; jj < 4; ++jj) w[jj] = Ms[k][cl + 16 * jj];
        #pragma unroll
        for (int ii = 0; ii < 4; ++ii)
            #pragma unroll
            for (int jj = 0; jj < 4; ++jj) acc[ii][jj] += a[ii] * w[jj];
    }
    #pragma unroll
    for (int ii = 0; ii < 4; ++ii)
        #pragma unroll
        for (int jj = 0; jj < 4; ++jj) {
            int row = r0 + rq * 4 + ii;
            int col = c0 + cl + 16 * jj;
            if (col < NCLS) out[row * NCLS + col] = acc[ii][jj] + bh[col];
        }
}

// ---------------- K9: orig_pred = X @ W_h + b_h  via bf16 MFMA, runs LAST ----------------
__global__ void __launch_bounds__(256) orig_mfma_kernel(const float* __restrict__ X,
                                                        const float* __restrict__ Wh,
                                                        const float* __restrict__ bh,
                                                        float* __restrict__ out) {
    __shared__ short As[128 * 32];   // row: 32 bf16 = 64B = 4 slots, slot XOR (row&3)
    __shared__ short Bs[128 * 32];   // "row" = output column c
    int t = threadIdx.x;
    int c0 = blockIdx.x * 128;
    int r0 = blockIdx.y * 128;
    int wid = t >> 6, l = t & 63;
    int lr = l & 15, lg = l >> 4;
    int wr = wid >> 1, wc = wid & 1;
    int ar = t >> 1, ah = t & 1;        // A staging: row, k-half(16)
    int bc = t & 127, bkh = t >> 7;     // B staging: col, k-half(16)
    int gc = c0 + bc;
    f32x4 acc[4][4] = {};
    for (int kk = 0; kk < DIM; kk += 32) {
        f32x4 va[4];
        const float* xrow = X + (size_t)(r0 + ar) * DIM + kk + ah * 16;
        #pragma unroll
        for (int q = 0; q < 4; ++q) va[q] = *(const f32x4*)(xrow + q * 4);
        float vb[16];
        #pragma unroll
        for (int k2 = 0; k2 < 16; ++k2)
            vb[k2] = (gc < NCLS) ? Wh[(size_t)(kk + bkh * 16 + k2) * NCLS + gc] : 0.f;
        __syncthreads();
        #pragma unroll
        for (int q2 = 0; q2 < 2; ++q2) {
            bf16x8 pk = pack8(va[2 * q2], va[2 * q2 + 1]);
            int slot = ah * 2 + q2;
            *(bf16x8*)((char*)As + ar * 64 + ((slot ^ (ar & 3)) << 4)) = pk;
        }
        #pragma unroll
        for (int q2 = 0; q2 < 2; ++q2) {
            bf16x8 pk;
            #pragma unroll
            for (int e = 0; e < 8; ++e) pk[e] = f2bf(vb[q2 * 8 + e]);
            int slot = bkh * 2 + q2;
            *(bf16x8*)((char*)Bs + bc * 64 + ((slot ^ (bc & 3)) << 4)) = pk;
        }
        __syncthreads();
        bf16x8 af[4], bfr[4];
        #pragma unroll
        for (int mi = 0; mi < 4; ++mi) {
            int row = wr * 64 + mi * 16 + lr;
            af[mi] = *(const bf16x8*)((char*)As + row * 64 + ((lg ^ (row & 3)) << 4));
        }
        #pragma unroll
        for (int ni = 0; ni < 4; ++ni) {
            int c = wc * 64 + ni * 16 + lr;
            bfr[ni] = *(const bf16x8*)((char*)Bs + c * 64 + ((lg ^ (c & 3)) << 4));
        }
        #pragma unroll
        for (int mi = 0; mi < 4; ++mi)
            #pragma unroll
            for (int ni = 0; ni < 4; ++ni)
                acc[mi][ni] = __builtin_amdgcn_mfma_f32_16x16x32_bf16(af[mi], bfr[ni], acc[mi][ni], 0, 0, 0);
    }
    #pragma unroll
    for (int mi = 0; mi < 4; ++mi) {
        int row = r0 + wr * 64 + mi * 16 + lg * 4;
        #pragma unroll
        for (int ni = 0; ni < 4; ++ni) {
            int col = c0 + wc * 64 + ni * 16 + lr;
            if (col < NCLS) {
                float bias = bh[col];
                #pragma unroll
                for (int r = 0; r < 4; ++r)
                    out[(size_t)(row + r) * NCLS + col] = acc[mi][ni][r] + bias;
            }
        }
    }
}

extern "C" void kernel_launch(void* const* d_in, const int* in_sizes, int n_in,
                              void* d_out, int out_size, void* d_ws, size_t ws_size,
                              hipStream_t stream) {
    const float* X    = (const float*)d_in[0];
    const float* cpt  = (const float*)d_in[1];
    const float* bank = (const float*)d_in[2];
    const float* Wh   = (const float*)d_in[3];
    const float* bh   = (const float*)d_in[4];
    float* out = (float*)d_out;

    float* orig  = out;
    float* ypred = out + Y_OFF;
    float* out3  = out + S_OFF;

    // Scratch lives inside the orig_pred region; orig_mfma (last) overwrites it
    // and reads only raw inputs.
    float* key     = out;                    // 6,400,000 floats
    float* bank_sq = out + 6400000;          //   100,000
    float* G       = out + 6500000;          //     4,096
    float* invG    = out + 6504096;          //     4,096
    float* B       = out + 6508192;          //   524,288
    float* M       = out + 7032480;          //    64,000
    float* dots    = out + 7096480;          //        64
    float* cand_v  = out + 7100000;          //   102,400
    int*   cand_j  = (int*)(out + 7202400);  //   102,400 ints
    short* cptT    = (short*)(out + 7304800); //  65,536 shorts (ends 7,337,568)

    g_kernel<<<4096, 256, 0, stream>>>(cpt, G);
    invert_kernel<<<1, 256, 0, stream>>>(G, invG);
    projB_kernel<<<BSZ / 4, 256, 0, stream>>>(X, cpt, invG, B);
    m_kernel<<<(NCLS + 15) / 16, 256, 0, stream>>>(cpt, Wh, M);
    cvt_cpt_kernel<<<256, 256, 0, stream>>>(cpt, cptT);
    dist_mfma_kernel<<<(NBANK + 127) / 128, 256, 0, stream>>>(bank, cptT, key, bank_sq);
    topA_kernel<<<NCON * NCHUNK, 256, 0, stream>>>(key, cand_v, cand_j);
    topB_kernel<<<NCON, 256, 0, stream>>>(cand_v, cand_j, bank_sq, dots);
    finalize_kernel<<<1, 256, 0, stream>>>(G, dots, out3);
    ypred_kernel<<<dim3(16, 128), 256, 0, stream>>>(B, M, bh, ypred);
    orig_mfma_kernel<<<dim3(8, 64), 256, 0, stream>>>(X, Wh, bh, orig);
}

// Round 4
// 767.269 us; speedup vs baseline: 5.8192x; 1.1697x over previous
//
#include <hip/hip_runtime.h>
#include <cstddef>

#define BSZ   8192
#define DIM   1024
#define NCON  64
#define NBANK 100000
#define NCLS  1000
#define TOPK  50
#define NCHUNK 32
#define CHUNK  3125   // 32 * 3125 = 100000

#define Y_OFF 8192000
#define S_OFF 16384000

typedef __attribute__((ext_vector_type(8))) short bf16x8;
typedef __attribute__((ext_vector_type(4))) float f32x4;

__device__ __forceinline__ short f2bf(float x) {
    unsigned u = __builtin_bit_cast(unsigned, x);
    unsigned r = (u + 0x7fffu + ((u >> 16) & 1u)) >> 16;
    return (short)r;
}

__device__ __forceinline__ bf16x8 pack8(f32x4 a, f32x4 b) {
    bf16x8 p;
    p[0] = f2bf(a[0]); p[1] = f2bf(a[1]); p[2] = f2bf(a[2]); p[3] = f2bf(a[3]);
    p[4] = f2bf(b[0]); p[5] = f2bf(b[1]); p[6] = f2bf(b[2]); p[7] = f2bf(b[3]);
    return p;
}

// ---------------- C1: Xbf[r][d] = bf16(X[r][d]) ----------------
__global__ void __launch_bounds__(256) cvt_x_kernel(const float* __restrict__ X,
                                                    short* __restrict__ Xbf) {
    size_t u = (size_t)(blockIdx.x * 256 + threadIdx.x) * 8;
    f32x4 a = *(const f32x4*)(X + u);
    f32x4 b = *(const f32x4*)(X + u + 4);
    *(bf16x8*)(Xbf + u) = pack8(a, b);
}

// ---------------- C2: cptT[n][d] = bf16(cpt[d][n]); cptR[d][n] = bf16(cpt[d][n]) ----------------
__global__ void __launch_bounds__(256) cvt_cpt_kernel(const float* __restrict__ cpt,
                                                      short* __restrict__ cptT,
                                                      short* __restrict__ cptR) {
    int u = blockIdx.x * 256 + threadIdx.x;   // 0..65535
    int d = u >> 6, n = u & 63;
    short v = f2bf(cpt[u]);
    cptR[u] = v;
    cptT[n * DIM + d] = v;
}

// ---------------- C3: WcatT[n][k] = bf16(Wh[k][n]) for n<1000, 0 for 1000<=n<1024 ----------------
__global__ void __launch_bounds__(256) cvt_whT_kernel(const float* __restrict__ Wh,
                                                      short* __restrict__ WcatT) {
    __shared__ short Ts[64][65];
    int k0 = blockIdx.x * 64, n0 = blockIdx.y * 64;
    int t = threadIdx.x;
    #pragma unroll
    for (int i = 0; i < 16; ++i) {
        int u = i * 256 + t;
        int kL = u >> 6, nL = u & 63;
        int n = n0 + nL;
        Ts[kL][nL] = (n < NCLS) ? f2bf(Wh[(size_t)(k0 + kL) * NCLS + n]) : (short)0;
    }
    __syncthreads();
    #pragma unroll
    for (int i = 0; i < 16; ++i) {
        int u = i * 256 + t;
        int nL = u >> 6, kL = u & 63;
        WcatT[(size_t)(n0 + nL) * DIM + k0 + kL] = Ts[kL][nL];
    }
}

// ---------------- K1: G = C^T C via MFMA (1 block), f32 out ----------------
__global__ void __launch_bounds__(256) g_mfma_kernel(const short* __restrict__ cptT,
                                                     float* __restrict__ G) {
    int t = threadIdx.x;
    int wid = t >> 6, l = t & 63, lr = l & 15, lg = l >> 4;
    f32x4 acc[4] = {};
    for (int kk = 0; kk < DIM; kk += 32) {
        bf16x8 af[4], bfr;
        #pragma unroll
        for (int mi = 0; mi < 4; ++mi)
            af[mi] = *(const bf16x8*)(cptT + (mi * 16 + lr) * DIM + kk + lg * 8);
        bfr = *(const bf16x8*)(cptT + (wid * 16 + lr) * DIM + kk + lg * 8);
        #pragma unroll
        for (int mi = 0; mi < 4; ++mi)
            acc[mi] = __builtin_amdgcn_mfma_f32_16x16x32_bf16(af[mi], bfr, acc[mi], 0, 0, 0);
    }
    #pragma unroll
    for (int mi = 0; mi < 4; ++mi)
        #pragma unroll
        for (int r = 0; r < 4; ++r)
            G[(mi * 16 + lg * 4 + r) * 64 + wid * 16 + lr] = acc[mi][r];
}

// ---------------- K2: invG via Gauss-Jordan ----------------
__global__ void __launch_bounds__(256) invert_kernel(const float* __restrict__ G,
                                                     float* __restrict__ invG) {
    __shared__ float Ag[64][129];
    __shared__ float fac[64];
    int t = threadIdx.x;
    for (int u = t; u < 64 * 64; u += 256) {
        int i = u >> 6, j = u & 63;
        Ag[i][j] = G[u];
        Ag[i][64 + j] = (i == j) ? 1.f : 0.f;
    }
    __syncthreads();
    for (int k = 0; k < 64; ++k) {
        float piv = Ag[k][k];
        __syncthreads();
        float rp = 1.f / piv;
        if (t < 128) Ag[k][t] *= rp;
        if (t < 64) fac[t] = (t == k) ? 0.f : Ag[t][k];
        __syncthreads();
        for (int u = t; u < 64 * 128; u += 256) {
            int i = u >> 7, j = u & 127;
            if (i != k) Ag[i][j] -= fac[i] * Ag[k][j];
        }
        __syncthreads();
    }
    for (int u = t; u < 64 * 64; u += 256)
        invG[u] = Ag[u >> 6][64 + (u & 63)];
}

// ---------------- K3: M[64][1024] = C^T @ Wh via MFMA (cols>=1000 auto-zero) ----------------
__global__ void __launch_bounds__(256) m_mfma_kernel(const short* __restrict__ cptT,
                                                     const short* __restrict__ WcatT,
                                                     float* __restrict__ M) {
    int t = threadIdx.x;
    int c0 = blockIdx.x * 128;
    int wid = t >> 6, l = t & 63, lr = l & 15, lg = l >> 4;
    f32x4 acc[4][2] = {};
    for (int kk = 0; kk < DIM; kk += 32) {
        bf16x8 af[4], bfr[2];
        #pragma unroll
        for (int mi = 0; mi < 4; ++mi)
            af[mi] = *(const bf16x8*)(cptT + (mi * 16 + lr) * DIM + kk + lg * 8);
        #pragma unroll
        for (int ni = 0; ni < 2; ++ni)
            bfr[ni] = *(const bf16x8*)(WcatT + (size_t)(c0 + wid * 32 + ni * 16 + lr) * DIM + kk + lg * 8);
        #pragma unroll
        for (int mi = 0; mi < 4; ++mi)
            #pragma unroll
            for (int ni = 0; ni < 2; ++ni)
                acc[mi][ni] = __builtin_amdgcn_mfma_f32_16x16x32_bf16(af[mi], bfr[ni], acc[mi][ni], 0, 0, 0);
    }
    #pragma unroll
    for (int mi = 0; mi < 4; ++mi)
        #pragma unroll
        for (int ni = 0; ni < 2; ++ni)
            #pragma unroll
            for (int r = 0; r < 4; ++r)
                M[(mi * 16 + lg * 4 + r) * 1024 + c0 + wid * 32 + ni * 16 + lr] = acc[mi][ni][r];
}

// ---------------- K4: M2T[c][n] = bf16( (invG @ M)[n][c] ) ----------------
__global__ void __launch_bounds__(256) m2t_kernel(const float* __restrict__ invG,
                                                  const float* __restrict__ M,
                                                  short* __restrict__ M2T) {
    __shared__ float Mt[64][129];
    __shared__ float iv[64][64];
    int t = threadIdx.x;
    int c0 = blockIdx.x * 128;
    for (int u = t; u < 8192; u += 256) { int j = u >> 7, c = u & 127; Mt[j][c] = M[j * 1024 + c0 + c]; }
    for (int u = t; u < 4096; u += 256) iv[u >> 6][u & 63] = invG[u];
    __syncthreads();
    int cl = t & 127, half = t >> 7;
    for (int nn = 0; nn < 32; ++nn) {
        int n = half * 32 + nn;
        float a = 0.f;
        #pragma unroll 16
        for (int j = 0; j < 64; ++j) a += iv[n][j] * Mt[j][cl];
        M2T[(size_t)(c0 + cl) * 64 + n] = f2bf(a);
    }
}

// ---------------- K5: WcatT[1024+c][d] = bf16( (C @ M2)[d][c] ) via MFMA ----------------
__global__ void __launch_bounds__(256) w2t_mfma_kernel(const short* __restrict__ M2T,
                                                       const short* __restrict__ cptR,
                                                       short* __restrict__ WcatT) {
    int t = threadIdx.x;
    int d0 = blockIdx.x * 128;
    int c0 = blockIdx.y * 128;
    int wid = t >> 6, l = t & 63, lr = l & 15, lg = l >> 4;
    int wr = wid >> 1, wc = wid & 1;
    f32x4 acc[4][4] = {};
    #pragma unroll
    for (int ks = 0; ks < 2; ++ks) {
        bf16x8 af[4], bfr[4];
        #pragma unroll
        for (int mi = 0; mi < 4; ++mi)
            af[mi] = *(const bf16x8*)(M2T + (size_t)(c0 + wr * 64 + mi * 16 + lr) * 64 + ks * 32 + lg * 8);
        #pragma unroll
        for (int ni = 0; ni < 4; ++ni)
            bfr[ni] = *(const bf16x8*)(cptR + (size_t)(d0 + wc * 64 + ni * 16 + lr) * 64 + ks * 32 + lg * 8);
        #pragma unroll
        for (int mi = 0; mi < 4; ++mi)
            #pragma unroll
            for (int ni = 0; ni < 4; ++ni)
                acc[mi][ni] = __builtin_amdgcn_mfma_f32_16x16x32_bf16(af[mi], bfr[ni], acc[mi][ni], 0, 0, 0);
    }
    #pragma unroll
    for (int mi = 0; mi < 4; ++mi)
        #pragma unroll
        for (int ni = 0; ni < 4; ++ni)
            #pragma unroll
            for (int r = 0; r < 4; ++r) {
                int c = c0 + wr * 64 + mi * 16 + lg * 4 + r;
                int d = d0 + wc * 64 + ni * 16 + lr;
                WcatT[(size_t)(1024 + c) * DIM + d] = f2bf(acc[mi][ni][r]);
            }
}

// ---------------- K6: dist via bf16 MFMA with register prefetch ----------------
__global__ void __launch_bounds__(256) dist_mfma_kernel(const float* __restrict__ bank,
                                                        const short* __restrict__ cptT,
                                                        float* __restrict__ key,
                                                        float* __restrict__ bank_sq) {
    __shared__ short Bt[128 * 64];   // row j: 64 bf16 = 128B = 8 slots, slot XOR (j&7)
    __shared__ float sqpart[256];
    __shared__ float sqs[128];
    int t = threadIdx.x;
    int j0 = blockIdx.x * 128;
    int wid = t >> 6, l = t & 63;
    int lr = l & 15, lg = l >> 4;
    int sj = t >> 1, sh = t & 1;
    bool jv = (j0 + sj) < NBANK;
    const float* srow = bank + (size_t)(j0 + sj) * DIM + sh * 32;
    float sqacc = 0.f;
    f32x4 acc[4][2] = {};
    f32x4 v[8];
    #pragma unroll
    for (int q = 0; q < 8; ++q)
        v[q] = jv ? *(const f32x4*)(srow + q * 4) : f32x4{0.f, 0.f, 0.f, 0.f};
    for (int kk = 0; kk < DIM; kk += 64) {
        f32x4 vn[8];
        int kn = (kk + 64 < DIM) ? kk + 64 : kk;   // last iter: dummy reload, discarded
        #pragma unroll
        for (int q = 0; q < 8; ++q)
            vn[q] = jv ? *(const f32x4*)(srow + kn + q * 4) : f32x4{0.f, 0.f, 0.f, 0.f};
        #pragma unroll
        for (int q = 0; q < 8; ++q)
            sqacc += v[q][0]*v[q][0] + v[q][1]*v[q][1] + v[q][2]*v[q][2] + v[q][3]*v[q][3];
        __syncthreads();
        #pragma unroll
        for (int q2 = 0; q2 < 4; ++q2) {
            bf16x8 pk = pack8(v[2 * q2], v[2 * q2 + 1]);
            int slot = sh * 4 + q2;
            *(bf16x8*)((char*)Bt + sj * 128 + ((slot ^ (sj & 7)) << 4)) = pk;
        }
        __syncthreads();
        #pragma unroll
        for (int ks = 0; ks < 2; ++ks) {
            bf16x8 af[4], bfr[2];
            #pragma unroll
            for (int mi = 0; mi < 4; ++mi)
                af[mi] = *(const bf16x8*)(cptT + (mi * 16 + lr) * DIM + kk + ks * 32 + lg * 8);
            #pragma unroll
            for (int ni = 0; ni < 2; ++ni) {
                int j = wid * 32 + ni * 16 + lr;
                int slot = ks * 4 + lg;
                bfr[ni] = *(const bf16x8*)((char*)Bt + j * 128 + ((slot ^ (j & 7)) << 4));
            }
            #pragma unroll
            for (int mi = 0; mi < 4; ++mi)
                #pragma unroll
                for (int ni = 0; ni < 2; ++ni)
                    acc[mi][ni] = __builtin_amdgcn_mfma_f32_16x16x32_bf16(af[mi], bfr[ni], acc[mi][ni], 0, 0, 0);
        }
        #pragma unroll
        for (int q = 0; q < 8; ++q) v[q] = vn[q];
    }
    sqpart[t] = sqacc;
    __syncthreads();
    if ((t & 1) == 0) {
        float s = sqpart[t] + sqpart[t + 1];
        sqs[sj] = s;
        if (jv) bank_sq[j0 + sj] = s;
    }
    __syncthreads();
    #pragma unroll
    for (int mi = 0; mi < 4; ++mi)
        #pragma unroll
        for (int ni = 0; ni < 2; ++ni) {
            int jl = wid * 32 + ni * 16 + lr;
            int j = j0 + jl;
            if (j < NBANK) {
                float s = sqs[jl];
                #pragma unroll
                for (int r = 0; r < 4; ++r) {
                    int m = mi * 16 + lg * 4 + r;
                    key[(size_t)m * NBANK + j] = s - 2.f * acc[mi][ni][r];
                }
            }
        }
}

// ---------------- K7a: per-(concept,chunk) top-50 via LDS iterative argmin ----------------
__global__ void __launch_bounds__(256) topA_kernel(const float* __restrict__ key,
                                                   float* __restrict__ cand_v,
                                                   int* __restrict__ cand_j) {
    int n = blockIdx.x >> 5;
    int c = blockIdx.x & 31;
    int base = c * CHUNK;
    const float* row = key + (size_t)n * NBANK + base;
    __shared__ float vals[CHUNK];
    __shared__ float wv[4];
    __shared__ int wj[4];
    int t = threadIdx.x;
    for (int j = t; j < CHUNK; j += 256) vals[j] = row[j];
    __syncthreads();
    float* cv = cand_v + (size_t)blockIdx.x * TOPK;
    int* cj = cand_j + (size_t)blockIdx.x * TOPK;
    for (int it = 0; it < TOPK; ++it) {
        float bv = __builtin_inff();
        int bj = 0x7fffffff;
        #pragma unroll 13
        for (int j = t; j < CHUNK; j += 256) {
            float v = vals[j];
            if (v < bv || (v == bv && j < bj)) { bv = v; bj = j; }
        }
        #pragma unroll
        for (int o = 32; o > 0; o >>= 1) {
            float ov = __shfl_down(bv, o);
            int oj = __shfl_down(bj, o);
            if (ov < bv || (ov == bv && oj < bj)) { bv = ov; bj = oj; }
        }
        if ((t & 63) == 0) { wv[t >> 6] = bv; wj[t >> 6] = bj; }
        __syncthreads();
        if (t == 0) {
            #pragma unroll
            for (int w = 1; w < 4; ++w)
                if (wv[w] < bv || (wv[w] == bv && wj[w] < bj)) { bv = wv[w]; bj = wj[w]; }
            cv[it] = bv;
            cj[it] = base + bj;
            vals[bj] = __builtin_inff();
        }
        __syncthreads();
    }
}

// ---------------- K7b: merge 32*50 candidates per concept ----------------
__global__ void __launch_bounds__(256) topB_kernel(const float* __restrict__ cand_v,
                                                   const int* __restrict__ cand_j,
                                                   const float* __restrict__ bank_sq,
                                                   float* __restrict__ dots) {
    int n = blockIdx.x;
    const int NC2 = NCHUNK * TOPK;  // 1600
    __shared__ float vals[NCHUNK * TOPK];
    __shared__ int gidx[NCHUNK * TOPK];
    __shared__ float wv[4];
    __shared__ int wj[4], wl[4];
    int t = threadIdx.x;
    for (int j = t; j < NC2; j += 256) {
        vals[j] = cand_v[(size_t)n * NC2 + j];
        gidx[j] = cand_j[(size_t)n * NC2 + j];
    }
    __syncthreads();
    float sum = 0.f;
    for (int it = 0; it < TOPK; ++it) {
        float bv = __builtin_inff();
        int bj = 0x7fffffff;
        int bl = -1;
        #pragma unroll 7
        for (int j = t; j < NC2; j += 256) {
            float v = vals[j];
            int gj = gidx[j];
            if (v < bv || (v == bv && gj < bj)) { bv = v; bj = gj; bl = j; }
        }
        #pragma unroll
        for (int o = 32; o > 0; o >>= 1) {
            float ov = __shfl_down(bv, o);
            int oj = __shfl_down(bj, o);
            int ol = __shfl_down(bl, o);
            if (ov < bv || (ov == bv && oj < bj)) { bv = ov; bj = oj; bl = ol; }
        }
        if ((t & 63) == 0) { wv[t >> 6] = bv; wj[t >> 6] = bj; wl[t >> 6] = bl; }
        __syncthreads();
        if (t == 0) {
            #pragma unroll
            for (int w = 1; w < 4; ++w)
                if (wv[w] < bv || (wv[w] == bv && wj[w] < bj)) { bv = wv[w]; bj = wj[w]; bl = wl[w]; }
            sum += 0.5f * (bank_sq[bj] - bv);
            vals[bl] = __builtin_inff();
        }
        __syncthreads();
    }
    if (t == 0) dots[n] = sum / (float)TOPK;
}

// ---------------- K8: the three scalars ----------------
__global__ void __launch_bounds__(256) finalize_kernel(const float* __restrict__ G,
                                                       const float* __restrict__ dots,
                                                       float* __restrict__ out3) {
    __shared__ float r1[256], r2[256], r3[256];
    int t = threadIdx.x;
    float sd = 0.f, so = 0.f;
    for (int u = t; u < 4096; u += 256) {
        float g = G[u];
        if ((u >> 6) == (u & 63)) sd += g; else so += g;
    }
    float s1 = (t < NCON) ? dots[t] : 0.f;
    r1[t] = sd; r2[t] = so; r3[t] = s1;
    __syncthreads();
    for (int o = 128; o > 0; o >>= 1) {
        if (t < o) { r1[t] += r1[t + o]; r2[t] += r2[t + o]; r3[t] += r3[t + o]; }
        __syncthreads();
    }
    if (t == 0) {
        out3[0] = r3[0] / 64.f;
        out3[1] = r2[0] / 4096.f;
        out3[2] = r1[0] / 4096.f;
    }
}

// ---------------- K9: fused [orig | y_pred] = Xbf @ WcatT^T + bias ----------------
// M=8192, N=2048 (cols 0..999 -> orig, 1024..2023 -> y_pred), K=1024, all bf16.
__global__ void __launch_bounds__(256) pred_kernel(const short* __restrict__ Xbf,
                                                   const short* __restrict__ WcatT,
                                                   const float* __restrict__ bh,
                                                   float* __restrict__ orig,
                                                   float* __restrict__ ypred) {
    __shared__ short As[128 * 64];   // row: 64 bf16 = 128B = 8 slots, XOR (row&7)
    __shared__ short Bs[128 * 64];
    int t = threadIdx.x;
    int c0 = blockIdx.x * 128;
    int r0 = blockIdx.y * 128;
    int wid = t >> 6, l = t & 63, lr = l & 15, lg = l >> 4;
    int wr = wid >> 1, wc = wid & 1;
    f32x4 acc[4][4] = {};
    for (int kk = 0; kk < DIM; kk += 64) {
        bf16x8 ra[4], rb[4];
        #pragma unroll
        for (int i = 0; i < 4; ++i) {
            int c = i * 256 + t;
            int row = c >> 3, slot = c & 7;
            ra[i] = *(const bf16x8*)(Xbf + (size_t)(r0 + row) * DIM + kk + slot * 8);
            rb[i] = *(const bf16x8*)(WcatT + (size_t)(c0 + row) * DIM + kk + slot * 8);
        }
        __syncthreads();
        #pragma unroll
        for (int i = 0; i < 4; ++i) {
            int c = i * 256 + t;
            int row = c >> 3, slot = c & 7;
            *(bf16x8*)((char*)As + row * 128 + ((slot ^ (row & 7)) << 4)) = ra[i];
            *(bf16x8*)((char*)Bs + row * 128 + ((slot ^ (row & 7)) << 4)) = rb[i];
        }
        __syncthreads();
        #pragma unroll
        for (int ks = 0; ks < 2; ++ks) {
            bf16x8 af[4], bfr[4];
            #pragma unroll
            for (int mi = 0; mi < 4; ++mi) {
                int rr = wr * 64 + mi * 16 + lr;
                int slot = ks * 4 + lg;
                af[mi] = *(const bf16x8*)((char*)As + rr * 128 + ((slot ^ (rr & 7)) << 4));
            }
            #pragma unroll
            for (int ni = 0; ni < 4; ++ni) {
                int nn2 = wc * 64 + ni * 16 + lr;
                int slot = ks * 4 + lg;
                bfr[ni] = *(const bf16x8*)((char*)Bs + nn2 * 128 + ((slot ^ (nn2 & 7)) << 4));
            }
            #pragma unroll
            for (int mi = 0; mi < 4; ++mi)
                #pragma unroll
                for (int ni = 0; ni < 4; ++ni)
                    acc[mi][ni] = __builtin_amdgcn_mfma_f32_16x16x32_bf16(af[mi], bfr[ni], acc[mi][ni], 0, 0, 0);
        }
    }
    #pragma unroll
    for (int mi = 0; mi < 4; ++mi)
        #pragma unroll
        for (int ni = 0; ni < 4; ++ni) {
            int cg = c0 + wc * 64 + ni * 16 + lr;
            bool isorig = cg < NCLS;
            bool isy = (cg >= 1024) && (cg < 1024 + NCLS);
            if (isorig || isy) {
                int cl = isorig ? cg : cg - 1024;
                float bias = bh[cl];
                float* dst = isorig ? orig : ypred;
                #pragma unroll
                for (int r = 0; r < 4; ++r) {
                    int row = r0 + wr * 64 + mi * 16 + lg * 4 + r;
                    dst[(size_t)row * NCLS + cl] = acc[mi][ni][r] + bias;
                }
            }
        }
}

extern "C" void kernel_launch(void* const* d_in, const int* in_sizes, int n_in,
                              void* d_out, int out_size, void* d_ws, size_t ws_size,
                              hipStream_t stream) {
    const float* X    = (const float*)d_in[0];
    const float* cpt  = (const float*)d_in[1];
    const float* bank = (const float*)d_in[2];
    const float* Wh   = (const float*)d_in[3];
    const float* bh   = (const float*)d_in[4];
    float* out = (float*)d_out;

    float* orig  = out;
    float* ypred = out + Y_OFF;
    float* out3  = out + S_OFF;

    // All scratch in d_ws (~48.5 MB used; ws is ~1.6 GB per profile fill size).
    char* w = (char*)d_ws;
    short* Xbf    = (short*)(w);               // 16,777,216 B
    short* WcatT  = (short*)(w + 16777216);    //  4,194,304 B  [2048][1024] bf16
    short* cptT   = (short*)(w + 20971520);    //    131,072 B  [64][1024]
    short* cptR   = (short*)(w + 21102592);    //    131,072 B  [1024][64]
    short* M2T    = (short*)(w + 21233664);    //    131,072 B  [1024][64]
    float* key    = (float*)(w + 21364736);    // 25,600,000 B
    float* bank_sq= (float*)(w + 46964736);    //    400,384 B
    float* G      = (float*)(w + 47365120);    //     16,384 B
    float* invG   = (float*)(w + 47381504);    //     16,384 B
    float* M      = (float*)(w + 47397888);    //    262,144 B  [64][1024] f32
    float* cand_v = (float*)(w + 47660032);    //    409,600 B
    int*   cand_j = (int*)  (w + 48069632);    //    409,600 B
    float* dots   = (float*)(w + 48479232);    //        256 B

    cvt_x_kernel<<<4096, 256, 0, stream>>>(X, Xbf);
    cvt_cpt_kernel<<<256, 256, 0, stream>>>(cpt, cptT, cptR);
    cvt_whT_kernel<<<dim3(16, 16), 256, 0, stream>>>(Wh, WcatT);
    g_mfma_kernel<<<1, 256, 0, stream>>>(cptT, G);
    invert_kernel<<<1, 256, 0, stream>>>(G, invG);
    m_mfma_kernel<<<8, 256, 0, stream>>>(cptT, WcatT, M);
    m2t_kernel<<<8, 256, 0, stream>>>(invG, M, M2T);
    w2t_mfma_kernel<<<dim3(8, 8), 256, 0, stream>>>(M2T, cptR, WcatT);
    dist_mfma_kernel<<<(NBANK + 127) / 128, 256, 0, stream>>>(bank, cptT, key, bank_sq);
    topA_kernel<<<NCON * NCHUNK, 256, 0, stream>>>(key, cand_v, cand_j);
    topB_kernel<<<NCON, 256, 0, stream>>>(cand_v, cand_j, bank_sq, dots);
    finalize_kernel<<<1, 256, 0, stream>>>(G, dots, out3);
    pred_kernel<<<dim3(16, 64), 256, 0, stream>>>(Xbf, WcatT, bh, orig, ypred);
}

// Round 5
// 760.750 us; speedup vs baseline: 5.8691x; 1.0086x over previous
//
#include <hip/hip_runtime.h>
#include <cstddef>

#define BSZ   8192
#define DIM   1024
#define NCON  64
#define NBANK 100000
#define NCLS  1000
#define TOPK  50
#define NCHUNK 32
#define CHUNK  3125   // 32 * 3125 = 100000

#define Y_OFF 8192000
#define S_OFF 16384000

typedef __attribute__((ext_vector_type(8))) short bf16x8;
typedef __attribute__((ext_vector_type(4))) float f32x4;

__device__ __forceinline__ short f2bf(float x) {
    unsigned u = __builtin_bit_cast(unsigned, x);
    unsigned r = (u + 0x7fffu + ((u >> 16) & 1u)) >> 16;
    return (short)r;
}

__device__ __forceinline__ bf16x8 pack8(f32x4 a, f32x4 b) {
    bf16x8 p;
    p[0] = f2bf(a[0]); p[1] = f2bf(a[1]); p[2] = f2bf(a[2]); p[3] = f2bf(a[3]);
    p[4] = f2bf(b[0]); p[5] = f2bf(b[1]); p[6] = f2bf(b[2]); p[7] = f2bf(b[3]);
    return p;
}

__device__ __forceinline__ void gload16(const short* g, short* l) {
    __builtin_amdgcn_global_load_lds(
        (__attribute__((address_space(1))) void*)g,
        (__attribute__((address_space(3))) void*)l,
        16, 0, 0);
}

// ---------------- C1: Xbf[r][d] = bf16(X[r][d]) ----------------
__global__ void __launch_bounds__(256) cvt_x_kernel(const float* __restrict__ X,
                                                    short* __restrict__ Xbf) {
    size_t u = (size_t)(blockIdx.x * 256 + threadIdx.x) * 8;
    f32x4 a = *(const f32x4*)(X + u);
    f32x4 b = *(const f32x4*)(X + u + 4);
    *(bf16x8*)(Xbf + u) = pack8(a, b);
}

// ---------------- C2: cptT[n][d] = bf16(cpt[d][n]); cptR[d][n] = bf16(cpt[d][n]) ----------------
__global__ void __launch_bounds__(256) cvt_cpt_kernel(const float* __restrict__ cpt,
                                                      short* __restrict__ cptT,
                                                      short* __restrict__ cptR) {
    int u = blockIdx.x * 256 + threadIdx.x;   // 0..65535
    int d = u >> 6, n = u & 63;
    short v = f2bf(cpt[u]);
    cptR[u] = v;
    cptT[n * DIM + d] = v;
}

// ---------------- C3: WcatT[n][k] = bf16(Wh[k][n]) for n<1000, 0 pad to 1024 ----------------
__global__ void __launch_bounds__(256) cvt_whT_kernel(const float* __restrict__ Wh,
                                                      short* __restrict__ WcatT) {
    __shared__ short Ts[64][65];
    int k0 = blockIdx.x * 64, n0 = blockIdx.y * 64;
    int t = threadIdx.x;
    #pragma unroll
    for (int i = 0; i < 16; ++i) {
        int u = i * 256 + t;
        int kL = u >> 6, nL = u & 63;
        int n = n0 + nL;
        Ts[kL][nL] = (n < NCLS) ? f2bf(Wh[(size_t)(k0 + kL) * NCLS + n]) : (short)0;
    }
    __syncthreads();
    #pragma unroll
    for (int i = 0; i < 16; ++i) {
        int u = i * 256 + t;
        int nL = u >> 6, kL = u & 63;
        WcatT[(size_t)(n0 + nL) * DIM + k0 + kL] = Ts[kL][nL];
    }
}

// ---------------- K1: G = C^T C via MFMA (1 block), f32 out ----------------
__global__ void __launch_bounds__(256) g_mfma_kernel(const short* __restrict__ cptT,
                                                     float* __restrict__ G) {
    int t = threadIdx.x;
    int wid = t >> 6, l = t & 63, lr = l & 15, lg = l >> 4;
    f32x4 acc[4] = {};
    for (int kk = 0; kk < DIM; kk += 32) {
        bf16x8 af[4], bfr;
        #pragma unroll
        for (int mi = 0; mi < 4; ++mi)
            af[mi] = *(const bf16x8*)(cptT + (mi * 16 + lr) * DIM + kk + lg * 8);
        bfr = *(const bf16x8*)(cptT + (wid * 16 + lr) * DIM + kk + lg * 8);
        #pragma unroll
        for (int mi = 0; mi < 4; ++mi)
            acc[mi] = __builtin_amdgcn_mfma_f32_16x16x32_bf16(af[mi], bfr, acc[mi], 0, 0, 0);
    }
    #pragma unroll
    for (int mi = 0; mi < 4; ++mi)
        #pragma unroll
        for (int r = 0; r < 4; ++r)
            G[(mi * 16 + lg * 4 + r) * 64 + wid * 16 + lr] = acc[mi][r];
}

// ---------------- K2: invG via Gauss-Jordan ----------------
__global__ void __launch_bounds__(256) invert_kernel(const float* __restrict__ G,
                                                     float* __restrict__ invG) {
    __shared__ float Ag[64][129];
    __shared__ float fac[64];
    int t = threadIdx.x;
    for (int u = t; u < 64 * 64; u += 256) {
        int i = u >> 6, j = u & 63;
        Ag[i][j] = G[u];
        Ag[i][64 + j] = (i == j) ? 1.f : 0.f;
    }
    __syncthreads();
    for (int k = 0; k < 64; ++k) {
        float piv = Ag[k][k];
        __syncthreads();
        float rp = 1.f / piv;
        if (t < 128) Ag[k][t] *= rp;
        if (t < 64) fac[t] = (t == k) ? 0.f : Ag[t][k];
        __syncthreads();
        for (int u = t; u < 64 * 128; u += 256) {
            int i = u >> 7, j = u & 127;
            if (i != k) Ag[i][j] -= fac[i] * Ag[k][j];
        }
        __syncthreads();
    }
    for (int u = t; u < 64 * 64; u += 256)
        invG[u] = Ag[u >> 6][64 + (u & 63)];
}

// ---------------- K3: M[64][1024] = C^T @ Wh via MFMA ----------------
__global__ void __launch_bounds__(256) m_mfma_kernel(const short* __restrict__ cptT,
                                                     const short* __restrict__ WcatT,
                                                     float* __restrict__ M) {
    int t = threadIdx.x;
    int c0 = blockIdx.x * 128;
    int wid = t >> 6, l = t & 63, lr = l & 15, lg = l >> 4;
    f32x4 acc[4][2] = {};
    for (int kk = 0; kk < DIM; kk += 32) {
        bf16x8 af[4], bfr[2];
        #pragma unroll
        for (int mi = 0; mi < 4; ++mi)
            af[mi] = *(const bf16x8*)(cptT + (mi * 16 + lr) * DIM + kk + lg * 8);
        #pragma unroll
        for (int ni = 0; ni < 2; ++ni)
            bfr[ni] = *(const bf16x8*)(WcatT + (size_t)(c0 + wid * 32 + ni * 16 + lr) * DIM + kk + lg * 8);
        #pragma unroll
        for (int mi = 0; mi < 4; ++mi)
            #pragma unroll
            for (int ni = 0; ni < 2; ++ni)
                acc[mi][ni] = __builtin_amdgcn_mfma_f32_16x16x32_bf16(af[mi], bfr[ni], acc[mi][ni], 0, 0, 0);
    }
    #pragma unroll
    for (int mi = 0; mi < 4; ++mi)
        #pragma unroll
        for (int ni = 0; ni < 2; ++ni)
            #pragma unroll
            for (int r = 0; r < 4; ++r)
                M[(mi * 16 + lg * 4 + r) * 1024 + c0 + wid * 32 + ni * 16 + lr] = acc[mi][ni][r];
}

// ---------------- K4: M2T[c][n] = bf16( (invG @ M)[n][c] ) ----------------
__global__ void __launch_bounds__(256) m2t_kernel(const float* __restrict__ invG,
                                                  const float* __restrict__ M,
                                                  short* __restrict__ M2T) {
    __shared__ float Mt[64][129];
    __shared__ float iv[64][64];
    int t = threadIdx.x;
    int c0 = blockIdx.x * 128;
    for (int u = t; u < 8192; u += 256) { int j = u >> 7, c = u & 127; Mt[j][c] = M[j * 1024 + c0 + c]; }
    for (int u = t; u < 4096; u += 256) iv[u >> 6][u & 63] = invG[u];
    __syncthreads();
    int cl = t & 127, half = t >> 7;
    for (int nn = 0; nn < 32; ++nn) {
        int n = half * 32 + nn;
        float a = 0.f;
        #pragma unroll 16
        for (int j = 0; j < 64; ++j) a += iv[n][j] * Mt[j][cl];
        M2T[(size_t)(c0 + cl) * 64 + n] = f2bf(a);
    }
}

// ---------------- K5: WcatT[1024+c][d] = bf16( (C @ M2)[d][c] ) via MFMA ----------------
__global__ void __launch_bounds__(256) w2t_mfma_kernel(const short* __restrict__ M2T,
                                                       const short* __restrict__ cptR,
                                                       short* __restrict__ WcatT) {
    int t = threadIdx.x;
    int d0 = blockIdx.x * 128;
    int c0 = blockIdx.y * 128;
    int wid = t >> 6, l = t & 63, lr = l & 15, lg = l >> 4;
    int wr = wid >> 1, wc = wid & 1;
    f32x4 acc[4][4] = {};
    #pragma unroll
    for (int ks = 0; ks < 2; ++ks) {
        bf16x8 af[4], bfr[4];
        #pragma unroll
        for (int mi = 0; mi < 4; ++mi)
            af[mi] = *(const bf16x8*)(M2T + (size_t)(c0 + wr * 64 + mi * 16 + lr) * 64 + ks * 32 + lg * 8);
        #pragma unroll
        for (int ni = 0; ni < 4; ++ni)
            bfr[ni] = *(const bf16x8*)(cptR + (size_t)(d0 + wc * 64 + ni * 16 + lr) * 64 + ks * 32 + lg * 8);
        #pragma unroll
        for (int mi = 0; mi < 4; ++mi)
            #pragma unroll
            for (int ni = 0; ni < 4; ++ni)
                acc[mi][ni] = __builtin_amdgcn_mfma_f32_16x16x32_bf16(af[mi], bfr[ni], acc[mi][ni], 0, 0, 0);
    }
    #pragma unroll
    for (int mi = 0; mi < 4; ++mi)
        #pragma unroll
        for (int ni = 0; ni < 4; ++ni)
            #pragma unroll
            for (int r = 0; r < 4; ++r) {
                int c = c0 + wr * 64 + mi * 16 + lg * 4 + r;
                int d = d0 + wc * 64 + ni * 16 + lr;
                WcatT[(size_t)(1024 + c) * DIM + d] = f2bf(acc[mi][ni][r]);
            }
}

// ---------------- K6: dist via bf16 MFMA, LDS-free (direct fragment loads) ----------------
// key[n][j] = bank_sq[j] - 2*(c_n . bank_j). B-fragments loaded straight from global
// in MFMA layout, converted f32->bf16 in-register; no barriers -> free pipelining.
__global__ void __launch_bounds__(256) dist_mfma_kernel(const float* __restrict__ bank,
                                                        const short* __restrict__ cptT,
                                                        float* __restrict__ key,
                                                        float* __restrict__ bank_sq) {
    int t = threadIdx.x;
    int j0 = blockIdx.x * 128;
    int wid = t >> 6, l = t & 63, lr = l & 15, lg = l >> 4;
    int j_[2]; bool v_[2];
    const float* brow[2];
    #pragma unroll
    for (int ni = 0; ni < 2; ++ni) {
        j_[ni] = j0 + wid * 32 + ni * 16 + lr;
        v_[ni] = j_[ni] < NBANK;
        brow[ni] = bank + (size_t)j_[ni] * DIM + lg * 8;
    }
    f32x4 acc[4][2] = {};
    float sq[2] = {0.f, 0.f};
    for (int kk = 0; kk < DIM; kk += 32) {
        bf16x8 af[4];
        #pragma unroll
        for (int mi = 0; mi < 4; ++mi)
            af[mi] = *(const bf16x8*)(cptT + (mi * 16 + lr) * DIM + kk + lg * 8);
        #pragma unroll
        for (int ni = 0; ni < 2; ++ni) {
            f32x4 a = v_[ni] ? *(const f32x4*)(brow[ni] + kk)     : f32x4{0.f, 0.f, 0.f, 0.f};
            f32x4 b = v_[ni] ? *(const f32x4*)(brow[ni] + kk + 4) : f32x4{0.f, 0.f, 0.f, 0.f};
            sq[ni] += a[0]*a[0] + a[1]*a[1] + a[2]*a[2] + a[3]*a[3]
                    + b[0]*b[0] + b[1]*b[1] + b[2]*b[2] + b[3]*b[3];
            bf16x8 bfr = pack8(a, b);
            #pragma unroll
            for (int mi = 0; mi < 4; ++mi)
                acc[mi][ni] = __builtin_amdgcn_mfma_f32_16x16x32_bf16(af[mi], bfr, acc[mi][ni], 0, 0, 0);
        }
    }
    // reduce sq over the 4 lg lanes (k-slices); butterfly leaves total in all lanes
    #pragma unroll
    for (int ni = 0; ni < 2; ++ni) {
        float s = sq[ni];
        s += __shfl_xor(s, 16);
        s += __shfl_xor(s, 32);
        sq[ni] = s;
        if (v_[ni] && lg == 0) bank_sq[j_[ni]] = s;
    }
    #pragma unroll
    for (int mi = 0; mi < 4; ++mi)
        #pragma unroll
        for (int ni = 0; ni < 2; ++ni)
            if (v_[ni]) {
                #pragma unroll
                for (int r = 0; r < 4; ++r) {
                    int m = mi * 16 + lg * 4 + r;
                    key[(size_t)m * NBANK + j_[ni]] = sq[ni] - 2.f * acc[mi][ni][r];
                }
            }
}

// ---------------- K7a: per-(concept,chunk) top-50 via LDS iterative argmin ----------------
__global__ void __launch_bounds__(256) topA_kernel(const float* __restrict__ key,
                                                   float* __restrict__ cand_v,
                                                   int* __restrict__ cand_j) {
    int n = blockIdx.x >> 5;
    int c = blockIdx.x & 31;
    int base = c * CHUNK;
    const float* row = key + (size_t)n * NBANK + base;
    __shared__ float vals[CHUNK];
    __shared__ float wv[4];
    __shared__ int wj[4];
    int t = threadIdx.x;
    for (int j = t; j < CHUNK; j += 256) vals[j] = row[j];
    __syncthreads();
    float* cv = cand_v + (size_t)blockIdx.x * TOPK;
    int* cj = cand_j + (size_t)blockIdx.x * TOPK;
    for (int it = 0; it < TOPK; ++it) {
        float bv = __builtin_inff();
        int bj = 0x7fffffff;
        #pragma unroll 13
        for (int j = t; j < CHUNK; j += 256) {
            float v = vals[j];
            if (v < bv || (v == bv && j < bj)) { bv = v; bj = j; }
        }
        #pragma unroll
        for (int o = 32; o > 0; o >>= 1) {
            float ov = __shfl_down(bv, o);
            int oj = __shfl_down(bj, o);
            if (ov < bv || (ov == bv && oj < bj)) { bv = ov; bj = oj; }
        }
        if ((t & 63) == 0) { wv[t >> 6] = bv; wj[t >> 6] = bj; }
        __syncthreads();
        if (t == 0) {
            #pragma unroll
            for (int w = 1; w < 4; ++w)
                if (wv[w] < bv || (wv[w] == bv && wj[w] < bj)) { bv = wv[w]; bj = wj[w]; }
            cv[it] = bv;
            cj[it] = base + bj;
            vals[bj] = __builtin_inff();
        }
        __syncthreads();
    }
}

// ---------------- K7b: merge 32*50 candidates per concept ----------------
__global__ void __launch_bounds__(256) topB_kernel(const float* __restrict__ cand_v,
                                                   const int* __restrict__ cand_j,
                                                   const float* __restrict__ bank_sq,
                                                   float* __restrict__ dots) {
    int n = blockIdx.x;
    const int NC2 = NCHUNK * TOPK;  // 1600
    __shared__ float vals[NCHUNK * TOPK];
    __shared__ int gidx[NCHUNK * TOPK];
    __shared__ float wv[4];
    __shared__ int wj[4], wl[4];
    int t = threadIdx.x;
    for (int j = t; j < NC2; j += 256) {
        vals[j] = cand_v[(size_t)n * NC2 + j];
        gidx[j] = cand_j[(size_t)n * NC2 + j];
    }
    __syncthreads();
    float sum = 0.f;
    for (int it = 0; it < TOPK; ++it) {
        float bv = __builtin_inff();
        int bj = 0x7fffffff;
        int bl = -1;
        #pragma unroll 7
        for (int j = t; j < NC2; j += 256) {
            float v = vals[j];
            int gj = gidx[j];
            if (v < bv || (v == bv && gj < bj)) { bv = v; bj = gj; bl = j; }
        }
        #pragma unroll
        for (int o = 32; o > 0; o >>= 1) {
            float ov = __shfl_down(bv, o);
            int oj = __shfl_down(bj, o);
            int ol = __shfl_down(bl, o);
            if (ov < bv || (ov == bv && oj < bj)) { bv = ov; bj = oj; bl = ol; }
        }
        if ((t & 63) == 0) { wv[t >> 6] = bv; wj[t >> 6] = bj; wl[t >> 6] = bl; }
        __syncthreads();
        if (t == 0) {
            #pragma unroll
            for (int w = 1; w < 4; ++w)
                if (wv[w] < bv || (wv[w] == bv && wj[w] < bj)) { bv = wv[w]; bj = wj[w]; bl = wl[w]; }
            sum += 0.5f * (bank_sq[bj] - bv);
            vals[bl] = __builtin_inff();
        }
        __syncthreads();
    }
    if (t == 0) dots[n] = sum / (float)TOPK;
}

// ---------------- K8: the three scalars ----------------
__global__ void __launch_bounds__(256) finalize_kernel(const float* __restrict__ G,
                                                       const float* __restrict__ dots,
                                                       float* __restrict__ out3) {
    __shared__ float r1[256], r2[256], r3[256];
    int t = threadIdx.x;
    float sd = 0.f, so = 0.f;
    for (int u = t; u < 4096; u += 256) {
        float g = G[u];
        if ((u >> 6) == (u & 63)) sd += g; else so += g;
    }
    float s1 = (t < NCON) ? dots[t] : 0.f;
    r1[t] = sd; r2[t] = so; r3[t] = s1;
    __syncthreads();
    for (int o = 128; o > 0; o >>= 1) {
        if (t < o) { r1[t] += r1[t + o]; r2[t] += r2[t + o]; r3[t] += r3[t + o]; }
        __syncthreads();
    }
    if (t == 0) {
        out3[0] = r3[0] / 64.f;
        out3[1] = r2[0] / 4096.f;
        out3[2] = r1[0] / 4096.f;
    }
}

// ---------------- K9: fused [orig | y_pred] = Xbf @ WcatT^T + bias ----------------
// global_load_lds staging: linear LDS dest, inverse-swizzled global source,
// XOR-swizzled ds_read (slot ^= row&7) -> conflict-free-ish b128 fragment reads.
__global__ void __launch_bounds__(256) pred_kernel(const short* __restrict__ Xbf,
                                                   const short* __restrict__ WcatT,
                                                   const float* __restrict__ bh,
                                                   float* __restrict__ orig,
                                                   float* __restrict__ ypred) {
    __shared__ short As[128 * 64];   // [row][64] bf16: row=128B=8 slots of 16B
    __shared__ short Bs[128 * 64];
    int t = threadIdx.x;
    int c0 = blockIdx.x * 128;
    int r0 = blockIdx.y * 128;
    int wid = t >> 6, l = t & 63, lr = l & 15, lg = l >> 4;
    int wr = wid >> 1, wc = wid & 1;
    // staging geometry: segment si covers rows si*8..si*8+7; lane l -> row si*8+(l>>3),
    // linear slot l&7, whose content must be global slot (l&7)^(l>>3).
    int srow_off = l >> 3;              // row within segment
    int scol = ((l & 7) ^ (l >> 3)) * 8; // inverse-swizzled global col (shorts)
    f32x4 acc[4][4] = {};
    for (int kk = 0; kk < DIM; kk += 64) {
        if (kk) __syncthreads();        // prev-iter fragment reads done
        #pragma unroll
        for (int i = 0; i < 4; ++i) {
            int si = wid * 4 + i;
            int row = si * 8 + srow_off;
            gload16(Xbf + (size_t)(r0 + row) * DIM + kk + scol, As + si * 512);
            gload16(WcatT + (size_t)(c0 + row) * DIM + kk + scol, Bs + si * 512);
        }
        __syncthreads();                // drains vmcnt -> staged data visible
        #pragma unroll
        for (int ks = 0; ks < 2; ++ks) {
            bf16x8 af[4], bfr[4];
            #pragma unroll
            for (int mi = 0; mi < 4; ++mi) {
                int rr = wr * 64 + mi * 16 + lr;
                int slot = (ks * 4 + lg) ^ (rr & 7);
                af[mi] = *(const bf16x8*)(As + rr * 64 + slot * 8);
            }
            #pragma unroll
            for (int ni = 0; ni < 4; ++ni) {
                int cc = wc * 64 + ni * 16 + lr;
                int slot = (ks * 4 + lg) ^ (cc & 7);
                bfr[ni] = *(const bf16x8*)(Bs + cc * 64 + slot * 8);
            }
            #pragma unroll
            for (int mi = 0; mi < 4; ++mi)
                #pragma unroll
                for (int ni = 0; ni < 4; ++ni)
                    acc[mi][ni] = __builtin_amdgcn_mfma_f32_16x16x32_bf16(af[mi], bfr[ni], acc[mi][ni], 0, 0, 0);
        }
    }
    #pragma unroll
    for (int mi = 0; mi < 4; ++mi)
        #pragma unroll
        for (int ni = 0; ni < 4; ++ni) {
            int cg = c0 + wc * 64 + ni * 16 + lr;
            bool isorig = cg < NCLS;
            bool isy = (cg >= 1024) && (cg < 1024 + NCLS);
            if (isorig || isy) {
                int cl = isorig ? cg : cg - 1024;
                float bias = bh[cl];
                float* dst = isorig ? orig : ypred;
                #pragma unroll
                for (int r = 0; r < 4; ++r) {
                    int row = r0 + wr * 64 + mi * 16 + lg * 4 + r;
                    dst[(size_t)row * NCLS + cl] = acc[mi][ni][r] + bias;
                }
            }
        }
}

extern "C" void kernel_launch(void* const* d_in, const int* in_sizes, int n_in,
                              void* d_out, int out_size, void* d_ws, size_t ws_size,
                              hipStream_t stream) {
    const float* X    = (const float*)d_in[0];
    const float* cpt  = (const float*)d_in[1];
    const float* bank = (const float*)d_in[2];
    const float* Wh   = (const float*)d_in[3];
    const float* bh   = (const float*)d_in[4];
    float* out = (float*)d_out;

    float* orig  = out;
    float* ypred = out + Y_OFF;
    float* out3  = out + S_OFF;

    char* w = (char*)d_ws;
    short* Xbf    = (short*)(w);               // 16,777,216 B
    short* WcatT  = (short*)(w + 16777216);    //  4,194,304 B  [2048][1024] bf16
    short* cptT   = (short*)(w + 20971520);    //    131,072 B  [64][1024]
    short* cptR   = (short*)(w + 21102592);    //    131,072 B  [1024][64]
    short* M2T    = (short*)(w + 21233664);    //    131,072 B  [1024][64]
    float* key    = (float*)(w + 21364736);    // 25,600,000 B
    float* bank_sq= (float*)(w + 46964736);    //    400,384 B
    float* G      = (float*)(w + 47365120);    //     16,384 B
    float* invG   = (float*)(w + 47381504);    //     16,384 B
    float* M      = (float*)(w + 47397888);    //    262,144 B  [64][1024] f32
    float* cand_v = (float*)(w + 47660032);    //    409,600 B
    int*   cand_j = (int*)  (w + 48069632);    //    409,600 B
    float* dots   = (float*)(w + 48479232);    //        256 B

    cvt_x_kernel<<<4096, 256, 0, stream>>>(X, Xbf);
    cvt_cpt_kernel<<<256, 256, 0, stream>>>(cpt, cptT, cptR);
    cvt_whT_kernel<<<dim3(16, 16), 256, 0, stream>>>(Wh, WcatT);
    g_mfma_kernel<<<1, 256, 0, stream>>>(cptT, G);
    invert_kernel<<<1, 256, 0, stream>>>(G, invG);
    m_mfma_kernel<<<8, 256, 0, stream>>>(cptT, WcatT, M);
    m2t_kernel<<<8, 256, 0, stream>>>(invG, M, M2T);
    w2t_mfma_kernel<<<dim3(8, 8), 256, 0, stream>>>(M2T, cptR, WcatT);
    dist_mfma_kernel<<<(NBANK + 127) / 128, 256, 0, stream>>>(bank, cptT, key, bank_sq);
    topA_kernel<<<NCON * NCHUNK, 256, 0, stream>>>(key, cand_v, cand_j);
    topB_kernel<<<NCON, 256, 0, stream>>>(cand_v, cand_j, bank_sq, dots);
    finalize_kernel<<<1, 256, 0, stream>>>(G, dots, out3);
    pred_kernel<<<dim3(16, 64), 256, 0, stream>>>(Xbf, WcatT, bh, orig, ypred);
}

// Round 6
// 736.776 us; speedup vs baseline: 6.0601x; 1.0325x over previous
//
#include <hip/hip_runtime.h>
#include <cstddef>

#define BSZ   8192
#define DIM   1024
#define NCON  64
#define NBANK 100000
#define NCLS  1000
#define TOPK  50
#define NCHUNK 32
#define CHUNK  3125    // 32 * 3125 = 100000
#define CHUNKP 3328    // 13 * 256 (padded with +inf)

#define Y_OFF 8192000
#define S_OFF 16384000

typedef __attribute__((ext_vector_type(8))) short bf16x8;
typedef __attribute__((ext_vector_type(4))) float f32x4;

__device__ __forceinline__ short f2bf(float x) {
    unsigned u = __builtin_bit_cast(unsigned, x);
    unsigned r = (u + 0x7fffu + ((u >> 16) & 1u)) >> 16;
    return (short)r;
}

__device__ __forceinline__ bf16x8 pack8(f32x4 a, f32x4 b) {
    bf16x8 p;
    p[0] = f2bf(a[0]); p[1] = f2bf(a[1]); p[2] = f2bf(a[2]); p[3] = f2bf(a[3]);
    p[4] = f2bf(b[0]); p[5] = f2bf(b[1]); p[6] = f2bf(b[2]); p[7] = f2bf(b[3]);
    return p;
}

__device__ __forceinline__ void gload16(const short* g, short* l) {
    __builtin_amdgcn_global_load_lds(
        (__attribute__((address_space(1))) void*)g,
        (__attribute__((address_space(3))) void*)l,
        16, 0, 0);
}

// ================= L1: prep =================
// blocks 0..4095: cvt_x ; 4096..4351: cvt_whT ; 4352: cpt convert + G (MFMA) + invG (GJ)
__global__ void __launch_bounds__(256) prep_kernel(const float* __restrict__ X,
                                                   const float* __restrict__ cpt,
                                                   const float* __restrict__ Wh,
                                                   short* __restrict__ Xbf,
                                                   short* __restrict__ WcatT,
                                                   short* __restrict__ cptT,
                                                   short* __restrict__ cptR,
                                                   float* __restrict__ G,
                                                   float* __restrict__ invG) {
    __shared__ __align__(16) char smem[33280];
    int b = blockIdx.x;
    int t = threadIdx.x;
    if (b < 4096) {
        size_t u = ((size_t)b * 256 + t) * 8;
        f32x4 a = *(const f32x4*)(X + u);
        f32x4 c = *(const f32x4*)(X + u + 4);
        *(bf16x8*)(Xbf + u) = pack8(a, c);
    } else if (b < 4352) {
        short* Ts = (short*)smem;   // [64][65]
        int q = b - 4096;
        int k0 = (q & 15) * 64, n0 = (q >> 4) * 64;
        #pragma unroll
        for (int i = 0; i < 16; ++i) {
            int u = i * 256 + t;
            int kL = u >> 6, nL = u & 63;
            int n = n0 + nL;
            Ts[kL * 65 + nL] = (n < NCLS) ? f2bf(Wh[(size_t)(k0 + kL) * NCLS + n]) : (short)0;
        }
        __syncthreads();
        #pragma unroll
        for (int i = 0; i < 16; ++i) {
            int u = i * 256 + t;
            int nL = u >> 6, kL = u & 63;
            WcatT[(size_t)(n0 + nL) * DIM + k0 + kL] = Ts[kL * 65 + nL];
        }
    } else {
        // --- convert cpt -> cptT, cptR ---
        for (int u = t; u < 65536; u += 256) {
            int d = u >> 6, n = u & 63;
            short v = f2bf(cpt[u]);
            cptR[u] = v;
            cptT[n * DIM + d] = v;
        }
        __syncthreads();   // drains vmcnt; own writes visible via L2
        // --- G = C^T C via MFMA from global cptT ---
        int wid = t >> 6, l = t & 63, lr = l & 15, lg = l >> 4;
        f32x4 acc[4] = {};
        for (int kk = 0; kk < DIM; kk += 32) {
            bf16x8 af[4], bfr;
            #pragma unroll
            for (int mi = 0; mi < 4; ++mi)
                af[mi] = *(const bf16x8*)(cptT + (mi * 16 + lr) * DIM + kk + lg * 8);
            bfr = *(const bf16x8*)(cptT + (wid * 16 + lr) * DIM + kk + lg * 8);
            #pragma unroll
            for (int mi = 0; mi < 4; ++mi)
                acc[mi] = __builtin_amdgcn_mfma_f32_16x16x32_bf16(af[mi], bfr, acc[mi], 0, 0, 0);
        }
        #pragma unroll
        for (int mi = 0; mi < 4; ++mi)
            #pragma unroll
            for (int r = 0; r < 4; ++r)
                G[(mi * 16 + lg * 4 + r) * 64 + wid * 16 + lr] = acc[mi][r];
        __syncthreads();   // G in L2, visible to own reads
        // --- Gauss-Jordan invert in LDS ---
        float* Ag = (float*)smem;            // [64][129]
        float* fac = (float*)(smem + 33024); // [64]
        for (int u = t; u < 64 * 64; u += 256) {
            int i = u >> 6, j = u & 63;
            Ag[i * 129 + j] = G[u];
            Ag[i * 129 + 64 + j] = (i == j) ? 1.f : 0.f;
        }
        __syncthreads();
        for (int k = 0; k < 64; ++k) {
            float piv = Ag[k * 129 + k];
            __syncthreads();
            float rp = 1.f / piv;
            if (t < 128) Ag[k * 129 + t] *= rp;
            if (t < 64) fac[t] = (t == k) ? 0.f : Ag[t * 129 + k];
            __syncthreads();
            for (int u = t; u < 64 * 128; u += 256) {
                int i = u >> 7, j = u & 127;
                if (i != k) Ag[i * 129 + j] -= fac[i] * Ag[k * 129 + j];
            }
            __syncthreads();
        }
        for (int u = t; u < 64 * 64; u += 256)
            invG[u] = Ag[(u >> 6) * 129 + 64 + (u & 63)];
    }
}

// ================= L2: mid =================
// blocks 0..781: dist (LDS-free MFMA) ; 782..789: M = C^T @ Wh
__global__ void __launch_bounds__(256) mid_kernel(const float* __restrict__ bank,
                                                  const short* __restrict__ cptT,
                                                  const short* __restrict__ WcatT,
                                                  float* __restrict__ key,
                                                  float* __restrict__ bank_sq,
                                                  float* __restrict__ M) {
    int b = blockIdx.x;
    int t = threadIdx.x;
    int wid = t >> 6, l = t & 63, lr = l & 15, lg = l >> 4;
    if (b < 782) {
        int j0 = b * 128;
        int j_[2]; bool v_[2];
        const float* brow[2];
        #pragma unroll
        for (int ni = 0; ni < 2; ++ni) {
            j_[ni] = j0 + wid * 32 + ni * 16 + lr;
            v_[ni] = j_[ni] < NBANK;
            brow[ni] = bank + (size_t)j_[ni] * DIM + lg * 8;
        }
        f32x4 acc[4][2] = {};
        float sq[2] = {0.f, 0.f};
        for (int kk = 0; kk < DIM; kk += 32) {
            bf16x8 af[4];
            #pragma unroll
            for (int mi = 0; mi < 4; ++mi)
                af[mi] = *(const bf16x8*)(cptT + (mi * 16 + lr) * DIM + kk + lg * 8);
            #pragma unroll
            for (int ni = 0; ni < 2; ++ni) {
                f32x4 a = v_[ni] ? *(const f32x4*)(brow[ni] + kk)     : f32x4{0.f, 0.f, 0.f, 0.f};
                f32x4 c = v_[ni] ? *(const f32x4*)(brow[ni] + kk + 4) : f32x4{0.f, 0.f, 0.f, 0.f};
                sq[ni] += a[0]*a[0] + a[1]*a[1] + a[2]*a[2] + a[3]*a[3]
                        + c[0]*c[0] + c[1]*c[1] + c[2]*c[2] + c[3]*c[3];
                bf16x8 bfr = pack8(a, c);
                #pragma unroll
                for (int mi = 0; mi < 4; ++mi)
                    acc[mi][ni] = __builtin_amdgcn_mfma_f32_16x16x32_bf16(af[mi], bfr, acc[mi][ni], 0, 0, 0);
            }
        }
        #pragma unroll
        for (int ni = 0; ni < 2; ++ni) {
            float s = sq[ni];
            s += __shfl_xor(s, 16);
            s += __shfl_xor(s, 32);
            sq[ni] = s;
            if (v_[ni] && lg == 0) bank_sq[j_[ni]] = s;
        }
        #pragma unroll
        for (int mi = 0; mi < 4; ++mi)
            #pragma unroll
            for (int ni = 0; ni < 2; ++ni)
                if (v_[ni]) {
                    #pragma unroll
                    for (int r = 0; r < 4; ++r) {
                        int m = mi * 16 + lg * 4 + r;
                        key[(size_t)m * NBANK + j_[ni]] = sq[ni] - 2.f * acc[mi][ni][r];
                    }
                }
    } else {
        int c0 = (b - 782) * 128;
        f32x4 acc[4][2] = {};
        for (int kk = 0; kk < DIM; kk += 32) {
            bf16x8 af[4], bfr[2];
            #pragma unroll
            for (int mi = 0; mi < 4; ++mi)
                af[mi] = *(const bf16x8*)(cptT + (mi * 16 + lr) * DIM + kk + lg * 8);
            #pragma unroll
            for (int ni = 0; ni < 2; ++ni)
                bfr[ni] = *(const bf16x8*)(WcatT + (size_t)(c0 + wid * 32 + ni * 16 + lr) * DIM + kk + lg * 8);
            #pragma unroll
            for (int mi = 0; mi < 4; ++mi)
                #pragma unroll
                for (int ni = 0; ni < 2; ++ni)
                    acc[mi][ni] = __builtin_amdgcn_mfma_f32_16x16x32_bf16(af[mi], bfr[ni], acc[mi][ni], 0, 0, 0);
        }
        #pragma unroll
        for (int mi = 0; mi < 4; ++mi)
            #pragma unroll
            for (int ni = 0; ni < 2; ++ni)
                #pragma unroll
                for (int r = 0; r < 4; ++r)
                    M[(mi * 16 + lg * 4 + r) * 1024 + c0 + wid * 32 + ni * 16 + lr] = acc[mi][ni][r];
    }
}

// ================= L3: topA =================
// per-thread cached (min,idx); extraction = shuffle reduce + single-thread rescan.
__global__ void __launch_bounds__(256) topA_kernel(const float* __restrict__ key,
                                                   float* __restrict__ cand_v,
                                                   int* __restrict__ cand_j) {
    int n = blockIdx.x >> 5;
    int c = blockIdx.x & 31;
    int base = c * CHUNK;
    const float* row = key + (size_t)n * NBANK + base;
    __shared__ float vals[CHUNKP];
    __shared__ float wv[4];
    __shared__ int wj[4];
    int t = threadIdx.x;
    float lv = __builtin_inff();
    int lj = 0x7fffffff;
    #pragma unroll 13
    for (int i = 0; i < 13; ++i) {
        int j = t + i * 256;
        float v = (j < CHUNK) ? row[j] : __builtin_inff();
        vals[j] = v;
        if (v < lv) { lv = v; lj = j; }   // ascending j -> earlier j wins ties
    }
    __syncthreads();
    float* cv = cand_v + (size_t)blockIdx.x * TOPK;
    int* cj = cand_j + (size_t)blockIdx.x * TOPK;
    for (int it = 0; it < TOPK; ++it) {
        float bv = lv; int bj = lj;
        #pragma unroll
        for (int o = 32; o > 0; o >>= 1) {
            float ov = __shfl_down(bv, o);
            int oj = __shfl_down(bj, o);
            if (ov < bv || (ov == bv && oj < bj)) { bv = ov; bj = oj; }
        }
        if ((t & 63) == 0) { wv[t >> 6] = bv; wj[t >> 6] = bj; }
        __syncthreads();
        float gv = wv[0]; int gj = wj[0];
        #pragma unroll
        for (int w = 1; w < 4; ++w)
            if (wv[w] < gv || (wv[w] == gv && wj[w] < gj)) { gv = wv[w]; gj = wj[w]; }
        if (t == 0) { cv[it] = gv; cj[it] = base + gj; }
        if (t == (gj & 255)) {
            vals[gj] = __builtin_inff();
            lv = __builtin_inff(); lj = 0x7fffffff;
            #pragma unroll 13
            for (int i = 0; i < 13; ++i) {
                int j = t + i * 256;
                float v = vals[j];
                if (v < lv) { lv = v; lj = j; }
            }
        }
        __syncthreads();
    }
}

// ================= L4: m2w2 + topB =================
// blocks 0..7: M2 = invG@M (chunk, LDS) then W2T = (C@M2)^T appended into WcatT
// blocks 8..71: merge 32*50 candidates per concept -> dots
__global__ void __launch_bounds__(256) m2w2_topB_kernel(const float* __restrict__ invG,
                                                        const float* __restrict__ M,
                                                        const short* __restrict__ cptR,
                                                        short* __restrict__ WcatT,
                                                        const float* __restrict__ cand_v,
                                                        const int* __restrict__ cand_j,
                                                        const float* __restrict__ bank_sq,
                                                        float* __restrict__ dots) {
    __shared__ __align__(16) char smem[49408];
    int b = blockIdx.x;
    int t = threadIdx.x;
    if (b < 8) {
        float* Mt = (float*)smem;            // [64][129]
        short* M2s = (short*)(smem + 33024); // [128][64] XOR-swizzled rows
        int c0 = b * 128;
        for (int u = t; u < 8192; u += 256) {
            int j = u >> 7, cc = u & 127;
            Mt[j * 129 + cc] = M[j * 1024 + c0 + cc];
        }
        __syncthreads();
        int cl = t & 127, half = t >> 7;
        for (int nn = 0; nn < 32; ++nn) {
            int n = half * 32 + nn;
            float a = 0.f;
            #pragma unroll 16
            for (int j = 0; j < 64; ++j) a += invG[n * 64 + j] * Mt[j * 129 + cl];
            int s = n >> 3;
            M2s[cl * 64 + (((s ^ (cl & 7)) << 3) | (n & 7))] = f2bf(a);
        }
        __syncthreads();
        int wid = t >> 6, l = t & 63, lr = l & 15, lg = l >> 4;
        int wr = wid >> 1, wc = wid & 1;
        for (int d0 = 0; d0 < DIM; d0 += 128) {
            f32x4 acc[4][4] = {};
            #pragma unroll
            for (int ks = 0; ks < 2; ++ks) {
                bf16x8 af[4], bfr[4];
                #pragma unroll
                for (int mi = 0; mi < 4; ++mi) {
                    int rr = wr * 64 + mi * 16 + lr;
                    int slot = (ks * 4 + lg) ^ (rr & 7);
                    af[mi] = *(const bf16x8*)(M2s + rr * 64 + slot * 8);
                }
                #pragma unroll
                for (int ni = 0; ni < 4; ++ni)
                    bfr[ni] = *(const bf16x8*)(cptR + (size_t)(d0 + wc * 64 + ni * 16 + lr) * 64 + ks * 32 + lg * 8);
                #pragma unroll
                for (int mi = 0; mi < 4; ++mi)
                    #pragma unroll
                    for (int ni = 0; ni < 4; ++ni)
                        acc[mi][ni] = __builtin_amdgcn_mfma_f32_16x16x32_bf16(af[mi], bfr[ni], acc[mi][ni], 0, 0, 0);
            }
            #pragma unroll
            for (int mi = 0; mi < 4; ++mi)
                #pragma unroll
                for (int ni = 0; ni < 4; ++ni)
                    #pragma unroll
                    for (int r = 0; r < 4; ++r) {
                        int cc = c0 + wr * 64 + mi * 16 + lg * 4 + r;
                        int d = d0 + wc * 64 + ni * 16 + lr;
                        WcatT[(size_t)(1024 + cc) * DIM + d] = f2bf(acc[mi][ni][r]);
                    }
        }
    } else {
        int n = b - 8;
        const int NC2 = NCHUNK * TOPK;  // 1600
        float* vals = (float*)smem;                 // 6400 B
        int* gidx = (int*)(smem + 6400);            // 6400 B
        float* wv = (float*)(smem + 12800);
        int* wj = (int*)(smem + 12816);
        int* wl = (int*)(smem + 12832);
        for (int j = t; j < NC2; j += 256) {
            vals[j] = cand_v[(size_t)n * NC2 + j];
            gidx[j] = cand_j[(size_t)n * NC2 + j];
        }
        __syncthreads();
        float sum = 0.f;
        for (int it = 0; it < TOPK; ++it) {
            float bv = __builtin_inff();
            int bj = 0x7fffffff;
            int bl = -1;
            #pragma unroll 7
            for (int j = t; j < NC2; j += 256) {
                float v = vals[j];
                int gj = gidx[j];
                if (v < bv || (v == bv && gj < bj)) { bv = v; bj = gj; bl = j; }
            }
            #pragma unroll
            for (int o = 32; o > 0; o >>= 1) {
                float ov = __shfl_down(bv, o);
                int oj = __shfl_down(bj, o);
                int ol = __shfl_down(bl, o);
                if (ov < bv || (ov == bv && oj < bj)) { bv = ov; bj = oj; bl = ol; }
            }
            if ((t & 63) == 0) { wv[t >> 6] = bv; wj[t >> 6] = bj; wl[t >> 6] = bl; }
            __syncthreads();
            if (t == 0) {
                #pragma unroll
                for (int w = 1; w < 4; ++w)
                    if (wv[w] < bv || (wv[w] == bv && wj[w] < bj)) { bv = wv[w]; bj = wj[w]; bl = wl[w]; }
                sum += 0.5f * (bank_sq[bj] - bv);
                vals[bl] = __builtin_inff();
            }
            __syncthreads();
        }
        if (t == 0) dots[n] = sum / (float)TOPK;
    }
}

// ================= L5: pred + finalize =================
// blocks 0..1023: fused [orig | y_pred] GEMM ; block 1024: the three scalars
__global__ void __launch_bounds__(256) pred_fin_kernel(const short* __restrict__ Xbf,
                                                       const short* __restrict__ WcatT,
                                                       const float* __restrict__ bh,
                                                       const float* __restrict__ G,
                                                       const float* __restrict__ dots,
                                                       float* __restrict__ orig,
                                                       float* __restrict__ ypred,
                                                       float* __restrict__ out3) {
    __shared__ __align__(16) char smem[32768];
    int b = blockIdx.x;
    int t = threadIdx.x;
    if (b < 1024) {
        short* As = (short*)smem;            // [128][64] bf16
        short* Bs = (short*)(smem + 16384);
        int c0 = (b & 15) * 128;
        int r0 = (b >> 4) * 128;
        int wid = t >> 6, l = t & 63, lr = l & 15, lg = l >> 4;
        int wr = wid >> 1, wc = wid & 1;
        int srow_off = l >> 3;
        int scol = ((l & 7) ^ (l >> 3)) * 8;
        f32x4 acc[4][4] = {};
        for (int kk = 0; kk < DIM; kk += 64) {
            if (kk) __syncthreads();
            #pragma unroll
            for (int i = 0; i < 4; ++i) {
                int si = wid * 4 + i;
                int row = si * 8 + srow_off;
                gload16(Xbf + (size_t)(r0 + row) * DIM + kk + scol, As + si * 512);
                gload16(WcatT + (size_t)(c0 + row) * DIM + kk + scol, Bs + si * 512);
            }
            __syncthreads();
            #pragma unroll
            for (int ks = 0; ks < 2; ++ks) {
                bf16x8 af[4], bfr[4];
                #pragma unroll
                for (int mi = 0; mi < 4; ++mi) {
                    int rr = wr * 64 + mi * 16 + lr;
                    int slot = (ks * 4 + lg) ^ (rr & 7);
                    af[mi] = *(const bf16x8*)(As + rr * 64 + slot * 8);
                }
                #pragma unroll
                for (int ni = 0; ni < 4; ++ni) {
                    int cc = wc * 64 + ni * 16 + lr;
                    int slot = (ks * 4 + lg) ^ (cc & 7);
                    bfr[ni] = *(const bf16x8*)(Bs + cc * 64 + slot * 8);
                }
                #pragma unroll
                for (int mi = 0; mi < 4; ++mi)
                    #pragma unroll
                    for (int ni = 0; ni < 4; ++ni)
                        acc[mi][ni] = __builtin_amdgcn_mfma_f32_16x16x32_bf16(af[mi], bfr[ni], acc[mi][ni], 0, 0, 0);
            }
        }
        #pragma unroll
        for (int mi = 0; mi < 4; ++mi)
            #pragma unroll
            for (int ni = 0; ni < 4; ++ni) {
                int cg = c0 + wc * 64 + ni * 16 + lr;
                bool isorig = cg < NCLS;
                bool isy = (cg >= 1024) && (cg < 1024 + NCLS);
                if (isorig || isy) {
                    int cl = isorig ? cg : cg - 1024;
                    float bias = bh[cl];
                    float* dst = isorig ? orig : ypred;
                    #pragma unroll
                    for (int r = 0; r < 4; ++r) {
                        int row = r0 + wr * 64 + mi * 16 + lg * 4 + r;
                        dst[(size_t)row * NCLS + cl] = acc[mi][ni][r] + bias;
                    }
                }
            }
    } else {
        float* r1 = (float*)smem;
        float* r2 = (float*)(smem + 1024);
        float* r3 = (float*)(smem + 2048);
        float sd = 0.f, so = 0.f;
        for (int u = t; u < 4096; u += 256) {
            float g = G[u];
            if ((u >> 6) == (u & 63)) sd += g; else so += g;
        }
        float s1 = (t < NCON) ? dots[t] : 0.f;
        r1[t] = sd; r2[t] = so; r3[t] = s1;
        __syncthreads();
        for (int o = 128; o > 0; o >>= 1) {
            if (t < o) { r1[t] += r1[t + o]; r2[t] += r2[t + o]; r3[t] += r3[t + o]; }
            __syncthreads();
        }
        if (t == 0) {
            out3[0] = r3[0] / 64.f;
            out3[1] = r2[0] / 4096.f;
            out3[2] = r1[0] / 4096.f;
        }
    }
}

extern "C" void kernel_launch(void* const* d_in, const int* in_sizes, int n_in,
                              void* d_out, int out_size, void* d_ws, size_t ws_size,
                              hipStream_t stream) {
    const float* X    = (const float*)d_in[0];
    const float* cpt  = (const float*)d_in[1];
    const float* bank = (const float*)d_in[2];
    const float* Wh   = (const float*)d_in[3];
    const float* bh   = (const float*)d_in[4];
    float* out = (float*)d_out;

    float* orig  = out;
    float* ypred = out + Y_OFF;
    float* out3  = out + S_OFF;

    char* w = (char*)d_ws;
    short* Xbf    = (short*)(w);               // 16,777,216 B
    short* WcatT  = (short*)(w + 16777216);    //  4,194,304 B  [2048][1024] bf16
    short* cptT   = (short*)(w + 20971520);    //    131,072 B  [64][1024]
    short* cptR   = (short*)(w + 21102592);    //    131,072 B  [1024][64]
    float* key    = (float*)(w + 21233664);    // 25,600,000 B
    float* bank_sq= (float*)(w + 46833664);    //    400,384 B
    float* G      = (float*)(w + 47234048);    //     16,384 B
    float* invG   = (float*)(w + 47250432);    //     16,384 B
    float* M      = (float*)(w + 47266816);    //    262,144 B  [64][1024] f32
    float* cand_v = (float*)(w + 47528960);    //    409,600 B
    int*   cand_j = (int*)  (w + 47938560);    //    409,600 B
    float* dots   = (float*)(w + 48348160);    //        256 B

    prep_kernel<<<4353, 256, 0, stream>>>(X, cpt, Wh, Xbf, WcatT, cptT, cptR, G, invG);
    mid_kernel<<<790, 256, 0, stream>>>(bank, cptT, WcatT, key, bank_sq, M);
    topA_kernel<<<NCON * NCHUNK, 256, 0, stream>>>(key, cand_v, cand_j);
    m2w2_topB_kernel<<<72, 256, 0, stream>>>(invG, M, cptR, WcatT, cand_v, cand_j, bank_sq, dots);
    pred_fin_kernel<<<1025, 256, 0, stream>>>(Xbf, WcatT, bh, G, dots, orig, ypred, out3);
}

// Round 7
// 440.800 us; speedup vs baseline: 10.1291x; 1.6715x over previous
//
#include <hip/hip_runtime.h>
#include <cstddef>

#define BSZ   8192
#define DIM   1024
#define NCON  64
#define NBANK 100000
#define NCLS  1000
#define TOPK  50
#define NCHUNK 32
#define CHUNK  3125    // 32 * 3125 = 100000
#define CHUNKP 3328    // 13 * 256 (padded with +inf)

#define Y_OFF 8192000
#define S_OFF 16384000

typedef __attribute__((ext_vector_type(8))) short bf16x8;
typedef __attribute__((ext_vector_type(4))) float f32x4;

__device__ __forceinline__ short f2bf(float x) {
    unsigned u = __builtin_bit_cast(unsigned, x);
    unsigned r = (u + 0x7fffu + ((u >> 16) & 1u)) >> 16;
    return (short)r;
}

__device__ __forceinline__ bf16x8 pack8(f32x4 a, f32x4 b) {
    bf16x8 p;
    p[0] = f2bf(a[0]); p[1] = f2bf(a[1]); p[2] = f2bf(a[2]); p[3] = f2bf(a[3]);
    p[4] = f2bf(b[0]); p[5] = f2bf(b[1]); p[6] = f2bf(b[2]); p[7] = f2bf(b[3]);
    return p;
}

__device__ __forceinline__ void gload16(const short* g, short* l) {
    __builtin_amdgcn_global_load_lds(
        (__attribute__((address_space(1))) void*)g,
        (__attribute__((address_space(3))) void*)l,
        16, 0, 0);
}

// ================= L1: prep (all-parallel converts) =================
// 0..4095: X->bf16 ; 4096..4351: Wh^T->bf16 (padded) ; 4352..4367: cpt->cptT,cptR
__global__ void __launch_bounds__(256) prep_kernel(const float* __restrict__ X,
                                                   const float* __restrict__ cpt,
                                                   const float* __restrict__ Wh,
                                                   short* __restrict__ Xbf,
                                                   short* __restrict__ WcatT,
                                                   short* __restrict__ cptT,
                                                   short* __restrict__ cptR) {
    __shared__ short Ts[64][65];
    int b = blockIdx.x;
    int t = threadIdx.x;
    if (b < 4096) {
        size_t u = ((size_t)b * 256 + t) * 8;
        f32x4 a = *(const f32x4*)(X + u);
        f32x4 c = *(const f32x4*)(X + u + 4);
        *(bf16x8*)(Xbf + u) = pack8(a, c);
    } else if (b < 4352) {
        int q = b - 4096;
        int k0 = (q & 15) * 64, n0 = (q >> 4) * 64;
        #pragma unroll
        for (int i = 0; i < 16; ++i) {
            int u = i * 256 + t;
            int kL = u >> 6, nL = u & 63;
            int n = n0 + nL;
            Ts[kL][nL] = (n < NCLS) ? f2bf(Wh[(size_t)(k0 + kL) * NCLS + n]) : (short)0;
        }
        __syncthreads();
        #pragma unroll
        for (int i = 0; i < 16; ++i) {
            int u = i * 256 + t;
            int nL = u >> 6, kL = u & 63;
            WcatT[(size_t)(n0 + nL) * DIM + k0 + kL] = Ts[kL][nL];
        }
    } else {
        int q = b - 4352;
        #pragma unroll
        for (int i = 0; i < 16; ++i) {
            int u = q * 4096 + i * 256 + t;
            int d = u >> 6, n = u & 63;
            short v = f2bf(cpt[u]);
            cptR[u] = v;
            cptT[n * DIM + d] = v;
        }
    }
}

// ================= L2: mid =================
// 0..781: dist (LDS-free MFMA) ; 782..789: M = C^T@Wh ; 790: G (MFMA) + invG (reg-GJ)
__global__ void __launch_bounds__(256) mid_kernel(const float* __restrict__ bank,
                                                  const short* __restrict__ cptT,
                                                  const short* __restrict__ WcatT,
                                                  float* __restrict__ key,
                                                  float* __restrict__ bank_sq,
                                                  float* __restrict__ M,
                                                  float* __restrict__ G,
                                                  float* __restrict__ invG) {
    __shared__ float rowk[64];
    __shared__ float fk[64];
    int b = blockIdx.x;
    int t = threadIdx.x;
    int wid = t >> 6, l = t & 63, lr = l & 15, lg = l >> 4;
    if (b < 782) {
        int j0 = b * 128;
        int j_[2]; bool v_[2];
        const float* brow[2];
        #pragma unroll
        for (int ni = 0; ni < 2; ++ni) {
            j_[ni] = j0 + wid * 32 + ni * 16 + lr;
            v_[ni] = j_[ni] < NBANK;
            brow[ni] = bank + (size_t)j_[ni] * DIM + lg * 8;
        }
        f32x4 acc[4][2] = {};
        float sq[2] = {0.f, 0.f};
        for (int kk = 0; kk < DIM; kk += 32) {
            bf16x8 af[4];
            #pragma unroll
            for (int mi = 0; mi < 4; ++mi)
                af[mi] = *(const bf16x8*)(cptT + (mi * 16 + lr) * DIM + kk + lg * 8);
            #pragma unroll
            for (int ni = 0; ni < 2; ++ni) {
                f32x4 a = v_[ni] ? *(const f32x4*)(brow[ni] + kk)     : f32x4{0.f, 0.f, 0.f, 0.f};
                f32x4 c = v_[ni] ? *(const f32x4*)(brow[ni] + kk + 4) : f32x4{0.f, 0.f, 0.f, 0.f};
                sq[ni] += a[0]*a[0] + a[1]*a[1] + a[2]*a[2] + a[3]*a[3]
                        + c[0]*c[0] + c[1]*c[1] + c[2]*c[2] + c[3]*c[3];
                bf16x8 bfr = pack8(a, c);
                #pragma unroll
                for (int mi = 0; mi < 4; ++mi)
                    acc[mi][ni] = __builtin_amdgcn_mfma_f32_16x16x32_bf16(af[mi], bfr, acc[mi][ni], 0, 0, 0);
            }
        }
        #pragma unroll
        for (int ni = 0; ni < 2; ++ni) {
            float s = sq[ni];
            s += __shfl_xor(s, 16);
            s += __shfl_xor(s, 32);
            sq[ni] = s;
            if (v_[ni] && lg == 0) bank_sq[j_[ni]] = s;
        }
        #pragma unroll
        for (int mi = 0; mi < 4; ++mi)
            #pragma unroll
            for (int ni = 0; ni < 2; ++ni)
                if (v_[ni]) {
                    #pragma unroll
                    for (int r = 0; r < 4; ++r) {
                        int m = mi * 16 + lg * 4 + r;
                        key[(size_t)m * NBANK + j_[ni]] = sq[ni] - 2.f * acc[mi][ni][r];
                    }
                }
    } else if (b < 790) {
        int c0 = (b - 782) * 128;
        f32x4 acc[4][2] = {};
        for (int kk = 0; kk < DIM; kk += 32) {
            bf16x8 af[4], bfr[2];
            #pragma unroll
            for (int mi = 0; mi < 4; ++mi)
                af[mi] = *(const bf16x8*)(cptT + (mi * 16 + lr) * DIM + kk + lg * 8);
            #pragma unroll
            for (int ni = 0; ni < 2; ++ni)
                bfr[ni] = *(const bf16x8*)(WcatT + (size_t)(c0 + wid * 32 + ni * 16 + lr) * DIM + kk + lg * 8);
            #pragma unroll
            for (int mi = 0; mi < 4; ++mi)
                #pragma unroll
                for (int ni = 0; ni < 2; ++ni)
                    acc[mi][ni] = __builtin_amdgcn_mfma_f32_16x16x32_bf16(af[mi], bfr[ni], acc[mi][ni], 0, 0, 0);
        }
        #pragma unroll
        for (int mi = 0; mi < 4; ++mi)
            #pragma unroll
            for (int ni = 0; ni < 2; ++ni)
                #pragma unroll
                for (int r = 0; r < 4; ++r)
                    M[(mi * 16 + lg * 4 + r) * 1024 + c0 + wid * 32 + ni * 16 + lr] = acc[mi][ni][r];
    } else {
        // --- G = C^T C via MFMA ---
        f32x4 acc[4] = {};
        for (int kk = 0; kk < DIM; kk += 32) {
            bf16x8 af[4], bfr;
            #pragma unroll
            for (int mi = 0; mi < 4; ++mi)
                af[mi] = *(const bf16x8*)(cptT + (mi * 16 + lr) * DIM + kk + lg * 8);
            bfr = *(const bf16x8*)(cptT + (wid * 16 + lr) * DIM + kk + lg * 8);
            #pragma unroll
            for (int mi = 0; mi < 4; ++mi)
                acc[mi] = __builtin_amdgcn_mfma_f32_16x16x32_bf16(af[mi], bfr, acc[mi], 0, 0, 0);
        }
        #pragma unroll
        for (int mi = 0; mi < 4; ++mi)
            #pragma unroll
            for (int r = 0; r < 4; ++r)
                G[(mi * 16 + lg * 4 + r) * 64 + wid * 16 + lr] = acc[mi][r];
        __syncthreads();   // drain vmcnt: G visible to own reads via L2
        // --- in-place Gauss-Jordan inverse, matrix in registers ---
        // thread t owns A[i][j] for i = 4s+wid (s=0..15), j = l.
        float myA[16];
        #pragma unroll
        for (int s = 0; s < 16; ++s) myA[s] = G[(4 * s + wid) * 64 + l];
        #pragma unroll
        for (int k = 0; k < 64; ++k) {
            if (wid == (k & 3)) rowk[l] = myA[k >> 2];   // original row k
            if (l == k) {                                 // original column k
                #pragma unroll
                for (int s = 0; s < 16; ++s) fk[4 * s + wid] = myA[s];
            }
            __syncthreads();
            float ip = 1.f / rowk[k];
            float rv = rowk[l];
            #pragma unroll
            for (int s = 0; s < 16; ++s) {
                int i = 4 * s + wid;
                float fv = fk[i];
                float nv;
                if (i == k && l == k)      nv = ip;
                else if (i == k)           nv = rv * ip;
                else if (l == k)           nv = -fv * ip;
                else                       nv = myA[s] - fv * (rv * ip);
                myA[s] = nv;
            }
            __syncthreads();
        }
        #pragma unroll
        for (int s = 0; s < 16; ++s) invG[(4 * s + wid) * 64 + l] = myA[s];
    }
}

// ================= L3: topA =================
__global__ void __launch_bounds__(256) topA_kernel(const float* __restrict__ key,
                                                   float* __restrict__ cand_v,
                                                   int* __restrict__ cand_j) {
    int n = blockIdx.x >> 5;
    int c = blockIdx.x & 31;
    int base = c * CHUNK;
    const float* row = key + (size_t)n * NBANK + base;
    __shared__ float vals[CHUNKP];
    __shared__ float wv[4];
    __shared__ int wj[4];
    int t = threadIdx.x;
    float lv = __builtin_inff();
    int lj = 0x7fffffff;
    #pragma unroll 13
    for (int i = 0; i < 13; ++i) {
        int j = t + i * 256;
        float v = (j < CHUNK) ? row[j] : __builtin_inff();
        vals[j] = v;
        if (v < lv) { lv = v; lj = j; }
    }
    __syncthreads();
    float* cv = cand_v + (size_t)blockIdx.x * TOPK;
    int* cj = cand_j + (size_t)blockIdx.x * TOPK;
    for (int it = 0; it < TOPK; ++it) {
        float bv = lv; int bj = lj;
        #pragma unroll
        for (int o = 32; o > 0; o >>= 1) {
            float ov = __shfl_down(bv, o);
            int oj = __shfl_down(bj, o);
            if (ov < bv || (ov == bv && oj < bj)) { bv = ov; bj = oj; }
        }
        if ((t & 63) == 0) { wv[t >> 6] = bv; wj[t >> 6] = bj; }
        __syncthreads();
        float gv = wv[0]; int gj = wj[0];
        #pragma unroll
        for (int w = 1; w < 4; ++w)
            if (wv[w] < gv || (wv[w] == gv && wj[w] < gj)) { gv = wv[w]; gj = wj[w]; }
        if (t == 0) { cv[it] = gv; cj[it] = base + gj; }
        if (t == (gj & 255)) {
            vals[gj] = __builtin_inff();
            lv = __builtin_inff(); lj = 0x7fffffff;
            #pragma unroll 13
            for (int i = 0; i < 13; ++i) {
                int j = t + i * 256;
                float v = vals[j];
                if (v < lv) { lv = v; lj = j; }
            }
        }
        __syncthreads();
    }
}

// ================= L4: m2w2 + topB =================
__global__ void __launch_bounds__(256) m2w2_topB_kernel(const float* __restrict__ invG,
                                                        const float* __restrict__ M,
                                                        const short* __restrict__ cptR,
                                                        short* __restrict__ WcatT,
                                                        const float* __restrict__ cand_v,
                                                        const int* __restrict__ cand_j,
                                                        const float* __restrict__ bank_sq,
                                                        float* __restrict__ dots) {
    __shared__ __align__(16) char smem[49408];
    int b = blockIdx.x;
    int t = threadIdx.x;
    if (b < 8) {
        float* Mt = (float*)smem;            // [64][129]
        short* M2s = (short*)(smem + 33024); // [128][64] XOR-swizzled rows
        int c0 = b * 128;
        for (int u = t; u < 8192; u += 256) {
            int j = u >> 7, cc = u & 127;
            Mt[j * 129 + cc] = M[j * 1024 + c0 + cc];
        }
        __syncthreads();
        int cl = t & 127, half = t >> 7;
        for (int nn = 0; nn < 32; ++nn) {
            int n = half * 32 + nn;
            float a = 0.f;
            #pragma unroll 16
            for (int j = 0; j < 64; ++j) a += invG[n * 64 + j] * Mt[j * 129 + cl];
            int s = n >> 3;
            M2s[cl * 64 + (((s ^ (cl & 7)) << 3) | (n & 7))] = f2bf(a);
        }
        __syncthreads();
        int wid = t >> 6, l = t & 63, lr = l & 15, lg = l >> 4;
        int wr = wid >> 1, wc = wid & 1;
        for (int d0 = 0; d0 < DIM; d0 += 128) {
            f32x4 acc[4][4] = {};
            #pragma unroll
            for (int ks = 0; ks < 2; ++ks) {
                bf16x8 af[4], bfr[4];
                #pragma unroll
                for (int mi = 0; mi < 4; ++mi) {
                    int rr = wr * 64 + mi * 16 + lr;
                    int slot = (ks * 4 + lg) ^ (rr & 7);
                    af[mi] = *(const bf16x8*)(M2s + rr * 64 + slot * 8);
                }
                #pragma unroll
                for (int ni = 0; ni < 4; ++ni)
                    bfr[ni] = *(const bf16x8*)(cptR + (size_t)(d0 + wc * 64 + ni * 16 + lr) * 64 + ks * 32 + lg * 8);
                #pragma unroll
                for (int mi = 0; mi < 4; ++mi)
                    #pragma unroll
                    for (int ni = 0; ni < 4; ++ni)
                        acc[mi][ni] = __builtin_amdgcn_mfma_f32_16x16x32_bf16(af[mi], bfr[ni], acc[mi][ni], 0, 0, 0);
            }
            #pragma unroll
            for (int mi = 0; mi < 4; ++mi)
                #pragma unroll
                for (int ni = 0; ni < 4; ++ni)
                    #pragma unroll
                    for (int r = 0; r < 4; ++r) {
                        int cc = c0 + wr * 64 + mi * 16 + lg * 4 + r;
                        int d = d0 + wc * 64 + ni * 16 + lr;
                        WcatT[(size_t)(1024 + cc) * DIM + d] = f2bf(acc[mi][ni][r]);
                    }
        }
    } else {
        int n = b - 8;
        const int NC2 = NCHUNK * TOPK;  // 1600
        float* vals = (float*)smem;
        int* gidx = (int*)(smem + 6400);
        float* wv = (float*)(smem + 12800);
        int* wj = (int*)(smem + 12816);
        int* wl = (int*)(smem + 12832);
        for (int j = t; j < NC2; j += 256) {
            vals[j] = cand_v[(size_t)n * NC2 + j];
            gidx[j] = cand_j[(size_t)n * NC2 + j];
        }
        __syncthreads();
        float sum = 0.f;
        for (int it = 0; it < TOPK; ++it) {
            float bv = __builtin_inff();
            int bj = 0x7fffffff;
            int bl = -1;
            #pragma unroll 7
            for (int j = t; j < NC2; j += 256) {
                float v = vals[j];
                int gj = gidx[j];
                if (v < bv || (v == bv && gj < bj)) { bv = v; bj = gj; bl = j; }
            }
            #pragma unroll
            for (int o = 32; o > 0; o >>= 1) {
                float ov = __shfl_down(bv, o);
                int oj = __shfl_down(bj, o);
                int ol = __shfl_down(bl, o);
                if (ov < bv || (ov == bv && oj < bj)) { bv = ov; bj = oj; bl = ol; }
            }
            if ((t & 63) == 0) { wv[t >> 6] = bv; wj[t >> 6] = bj; wl[t >> 6] = bl; }
            __syncthreads();
            if (t == 0) {
                #pragma unroll
                for (int w = 1; w < 4; ++w)
                    if (wv[w] < bv || (wv[w] == bv && wj[w] < bj)) { bv = wv[w]; bj = wj[w]; bl = wl[w]; }
                sum += 0.5f * (bank_sq[bj] - bv);
                vals[bl] = __builtin_inff();
            }
            __syncthreads();
        }
        if (t == 0) dots[n] = sum / (float)TOPK;
    }
}

// ================= L5: pred + finalize =================
__global__ void __launch_bounds__(256) pred_fin_kernel(const short* __restrict__ Xbf,
                                                       const short* __restrict__ WcatT,
                                                       const float* __restrict__ bh,
                                                       const float* __restrict__ G,
                                                       const float* __restrict__ dots,
                                                       float* __restrict__ orig,
                                                       float* __restrict__ ypred,
                                                       float* __restrict__ out3) {
    __shared__ __align__(16) char smem[32768];
    int b = blockIdx.x;
    int t = threadIdx.x;
    if (b < 1024) {
        short* As = (short*)smem;            // [128][64] bf16
        short* Bs = (short*)(smem + 16384);
        int c0 = (b & 15) * 128;
        int r0 = (b >> 4) * 128;
        int wid = t >> 6, l = t & 63, lr = l & 15, lg = l >> 4;
        int wr = wid >> 1, wc = wid & 1;
        int srow_off = l >> 3;
        int scol = ((l & 7) ^ (l >> 3)) * 8;
        f32x4 acc[4][4] = {};
        for (int kk = 0; kk < DIM; kk += 64) {
            if (kk) __syncthreads();
            #pragma unroll
            for (int i = 0; i < 4; ++i) {
                int si = wid * 4 + i;
                int row = si * 8 + srow_off;
                gload16(Xbf + (size_t)(r0 + row) * DIM + kk + scol, As + si * 512);
                gload16(WcatT + (size_t)(c0 + row) * DIM + kk + scol, Bs + si * 512);
            }
            __syncthreads();
            #pragma unroll
            for (int ks = 0; ks < 2; ++ks) {
                bf16x8 af[4], bfr[4];
                #pragma unroll
                for (int mi = 0; mi < 4; ++mi) {
                    int rr = wr * 64 + mi * 16 + lr;
                    int slot = (ks * 4 + lg) ^ (rr & 7);
                    af[mi] = *(const bf16x8*)(As + rr * 64 + slot * 8);
                }
                #pragma unroll
                for (int ni = 0; ni < 4; ++ni) {
                    int cc = wc * 64 + ni * 16 + lr;
                    int slot = (ks * 4 + lg) ^ (cc & 7);
                    bfr[ni] = *(const bf16x8*)(Bs + cc * 64 + slot * 8);
                }
                #pragma unroll
                for (int mi = 0; mi < 4; ++mi)
                    #pragma unroll
                    for (int ni = 0; ni < 4; ++ni)
                        acc[mi][ni] = __builtin_amdgcn_mfma_f32_16x16x32_bf16(af[mi], bfr[ni], acc[mi][ni], 0, 0, 0);
            }
        }
        #pragma unroll
        for (int mi = 0; mi < 4; ++mi)
            #pragma unroll
            for (int ni = 0; ni < 4; ++ni) {
                int cg = c0 + wc * 64 + ni * 16 + lr;
                bool isorig = cg < NCLS;
                bool isy = (cg >= 1024) && (cg < 1024 + NCLS);
                if (isorig || isy) {
                    int cl = isorig ? cg : cg - 1024;
                    float bias = bh[cl];
                    float* dst = isorig ? orig : ypred;
                    #pragma unroll
                    for (int r = 0; r < 4; ++r) {
                        int row = r0 + wr * 64 + mi * 16 + lg * 4 + r;
                        dst[(size_t)row * NCLS + cl] = acc[mi][ni][r] + bias;
                    }
                }
            }
    } else {
        float* r1 = (float*)smem;
        float* r2 = (float*)(smem + 1024);
        float* r3 = (float*)(smem + 2048);
        float sd = 0.f, so = 0.f;
        for (int u = t; u < 4096; u += 256) {
            float g = G[u];
            if ((u >> 6) == (u & 63)) sd += g; else so += g;
        }
        float s1 = (t < NCON) ? dots[t] : 0.f;
        r1[t] = sd; r2[t] = so; r3[t] = s1;
        __syncthreads();
        for (int o = 128; o > 0; o >>= 1) {
            if (t < o) { r1[t] += r1[t + o]; r2[t] += r2[t + o]; r3[t] += r3[t + o]; }
            __syncthreads();
        }
        if (t == 0) {
            out3[0] = r3[0] / 64.f;
            out3[1] = r2[0] / 4096.f;
            out3[2] = r1[0] / 4096.f;
        }
    }
}

extern "C" void kernel_launch(void* const* d_in, const int* in_sizes, int n_in,
                              void* d_out, int out_size, void* d_ws, size_t ws_size,
                              hipStream_t stream) {
    const float* X    = (const float*)d_in[0];
    const float* cpt  = (const float*)d_in[1];
    const float* bank = (const float*)d_in[2];
    const float* Wh   = (const float*)d_in[3];
    const float* bh   = (const float*)d_in[4];
    float* out = (float*)d_out;

    float* orig  = out;
    float* ypred = out + Y_OFF;
    float* out3  = out + S_OFF;

    char* w = (char*)d_ws;
    short* Xbf    = (short*)(w);               // 16,777,216 B
    short* WcatT  = (short*)(w + 16777216);    //  4,194,304 B  [2048][1024] bf16
    short* cptT   = (short*)(w + 20971520);    //    131,072 B  [64][1024]
    short* cptR   = (short*)(w + 21102592);    //    131,072 B  [1024][64]
    float* key    = (float*)(w + 21233664);    // 25,600,000 B
    float* bank_sq= (float*)(w + 46833664);    //    400,384 B
    float* G      = (float*)(w + 47234048);    //     16,384 B
    float* invG   = (float*)(w + 47250432);    //     16,384 B
    float* M      = (float*)(w + 47266816);    //    262,144 B  [64][1024] f32
    float* cand_v = (float*)(w + 47528960);    //    409,600 B
    int*   cand_j = (int*)  (w + 47938560);    //    409,600 B
    float* dots   = (float*)(w + 48348160);    //        256 B

    prep_kernel<<<4368, 256, 0, stream>>>(X, cpt, Wh, Xbf, WcatT, cptT, cptR);
    mid_kernel<<<791, 256, 0, stream>>>(bank, cptT, WcatT, key, bank_sq, M, G, invG);
    topA_kernel<<<NCON * NCHUNK, 256, 0, stream>>>(key, cand_v, cand_j);
    m2w2_topB_kernel<<<72, 256, 0, stream>>>(invG, M, cptR, WcatT, cand_v, cand_j, bank_sq, dots);
    pred_fin_kernel<<<1025, 256, 0, stream>>>(Xbf, WcatT, bh, G, dots, orig, ypred, out3);
}